// Round 20
// baseline (260.482 us; speedup 1.0000x reference)
//
#include <hip/hip_runtime.h>
#include <hip/hip_bf16.h>

typedef __bf16 bf16x8 __attribute__((ext_vector_type(8)));
typedef float f32x4 __attribute__((ext_vector_type(4)));

#define LAMBDA_INIT 0.3555090675909693f
#define CEXP 0.18033688011112042f   // 0.125 * log2(e), folded into Q at projection

// ws layout (bytes):
//  q    : [0, 4.19M)       bf16 [16384][128] row-major, PRE-SCALED by CEXP
//  kimg : [4.19M, 8.39M)   bf16 [4][64][2][8 regions][64 slots][8]  (frag image)
//  vimg : [8.39M, 12.58M)  bf16 [4][64][16 regions][64 slots][8]    (frag image)
//  part : [12.58M, +68.2M) recs x 16640B (l[64] f32 + O[64][128] bf16), 8 slots/(b,t)
//  WT   : after part       bf16 W'[384][1024]
#define K_OFF   ((size_t)16384 * 128)
#define VT_OFF  ((size_t)2 * 16384 * 128)
#define PART_OFF_BYTES ((size_t)12582912)
#define REC_FLOATS 4160  // 64 l + 4096 words of bf16 O

__device__ __forceinline__ unsigned short f2bf(float f) {
    __hip_bfloat16 h = __float2bfloat16(f);
    unsigned short u;
    __builtin_memcpy(&u, &h, 2);
    return u;
}
__device__ __forceinline__ float bf2f(unsigned short u) {
    unsigned int x = ((unsigned int)u) << 16;
    float f;
    __builtin_memcpy(&f, &x, 4);
    return f;
}
__device__ __forceinline__ unsigned int cvt_pk_bf16(float a, float b) {
    unsigned int r;
    asm volatile("v_cvt_pk_bf16_f32 %0, %1, %2" : "=v"(r) : "v"(a), "v"(b));
    return r;
}

// ---------------- W pre-transpose: [1024][128] f32 -> [128][1024] bf16 ----------------
__global__ __launch_bounds__(256) void prep_wt(
    const float* __restrict__ Wq, const float* __restrict__ Wk,
    const float* __restrict__ Wv, unsigned short* __restrict__ WT) {
    const int kt = blockIdx.x, nt = blockIdx.y, mat = blockIdx.z;
    const float* W = (mat == 0) ? Wq : (mat == 1) ? Wk : Wv;
    unsigned short* O = WT + (size_t)mat * 128 * 1024;
    __shared__ float tb[64][65];
    const int r = threadIdx.x >> 2, c4 = (threadIdx.x & 3) * 16;
    for (int j = 0; j < 4; ++j) {
        float4 v = *(const float4*)&W[(size_t)(kt * 64 + r) * 128 + nt * 64 + c4 + j * 4];
        tb[r][c4 + j * 4 + 0] = v.x;
        tb[r][c4 + j * 4 + 1] = v.y;
        tb[r][c4 + j * 4 + 2] = v.z;
        tb[r][c4 + j * 4 + 3] = v.w;
    }
    __syncthreads();
    unsigned short tmp[16];
    for (int j = 0; j < 16; ++j) tmp[j] = f2bf(tb[c4 + j][r]);
    *(uint4*)&O[(size_t)(nt * 64 + r) * 1024 + kt * 64 + c4] = *(uint4*)&tmp[0];
    *(uint4*)&O[(size_t)(nt * 64 + r) * 1024 + kt * 64 + c4 + 8] = *(uint4*)&tmp[8];
}

// ---------------- Fused QKV GEMM, N-split: grid (256 row-tiles, 2 N-halves) ----------
__global__ __launch_bounds__(512) void qkv_fused(
    const float* __restrict__ x, const unsigned short* __restrict__ WT,
    unsigned short* __restrict__ qkv) {
    const int tid = threadIdx.x;
    const int l = tid & 63, w = tid >> 6;
    const int g = l >> 4, i16 = l & 15;
    const int rh = w >> 2, cp = w & 3;
    const int row0 = blockIdx.x * 64;
    const int np = blockIdx.y;
    const unsigned short* Wt = WT + (size_t)np * 192 * 1024;

    __shared__ unsigned short xs[64][72];
    __shared__ unsigned short wt[192][72];

    f32x4 acc[2][3];
    const f32x4 z4 = {0.f, 0.f, 0.f, 0.f};
    for (int rt = 0; rt < 2; ++rt)
        for (int ct = 0; ct < 3; ++ct) acc[rt][ct] = z4;

    const int xrow = tid >> 3, xcol = (tid & 7) * 8;
    const int wn = tid >> 3, wk8 = (tid & 7) * 8;
    const float* xp = &x[(size_t)(row0 + xrow) * 1024 + xcol];
    const unsigned short* wp = &Wt[(size_t)wn * 1024 + wk8];

    float4 ax0, ax1;
    uint4 aw0, aw1, aw2;

#define QI(k0_) do {                                                        \
        ax0 = *(const float4*)&xp[(k0_)];                                   \
        ax1 = *(const float4*)&xp[(k0_) + 4];                               \
        aw0 = *(const uint4*)&wp[(k0_)];                                    \
        aw1 = *(const uint4*)&wp[64 * 1024 + (k0_)];                        \
        aw2 = *(const uint4*)&wp[128 * 1024 + (k0_)];                       \
    } while (0)

#define QS() do {                                                           \
        *(ushort4*)&xs[xrow][xcol]     = make_ushort4(f2bf(ax0.x), f2bf(ax0.y), f2bf(ax0.z), f2bf(ax0.w)); \
        *(ushort4*)&xs[xrow][xcol + 4] = make_ushort4(f2bf(ax1.x), f2bf(ax1.y), f2bf(ax1.z), f2bf(ax1.w)); \
        *(uint4*)&wt[wn +   0][wk8] = aw0;                                  \
        *(uint4*)&wt[wn +  64][wk8] = aw1;                                  \
        *(uint4*)&wt[wn + 128][wk8] = aw2;                                  \
    } while (0)

    QI(0);
    #pragma unroll 1
    for (int k0 = 0; k0 < 1024; k0 += 64) {
        __syncthreads();
        QS();
        if (k0 + 64 < 1024) QI(k0 + 64);
        __syncthreads();
        bf16x8 af[2][2];
        #pragma unroll
        for (int rt = 0; rt < 2; ++rt)
            for (int cc = 0; cc < 2; ++cc)
                af[rt][cc] = *(const bf16x8*)&xs[rh * 32 + rt * 16 + i16][cc * 32 + 8 * g];
        #pragma unroll
        for (int ct = 0; ct < 3; ++ct)
            for (int cc = 0; cc < 2; ++cc) {
                bf16x8 bb = *(const bf16x8*)&wt[cp * 48 + ct * 16 + i16][cc * 32 + 8 * g];
                for (int rt = 0; rt < 2; ++rt)
                    acc[rt][ct] = __builtin_amdgcn_mfma_f32_16x16x32_bf16(af[rt][cc], bb, acc[rt][ct], 0, 0, 0);
            }
    }
#undef QI
#undef QS

    __syncthreads();
    unsigned short(*ts)[200] = (unsigned short(*)[200]) & wt[0][0];
    #pragma unroll
    for (int rt = 0; rt < 2; ++rt)
        for (int ct = 0; ct < 3; ++ct) {
            const float sc = (np == 0 && cp * 48 + ct * 16 < 128) ? CEXP : 1.0f;
            for (int r = 0; r < 4; ++r)
                ts[rh * 32 + rt * 16 + g * 4 + r][cp * 48 + ct * 16 + i16] = f2bf(acc[rt][ct][r] * sc);
        }
    __syncthreads();

    const int bq = row0 >> 12;
    const int s = (row0 >> 6) & 63;
    if (np == 0) {
        {
            unsigned short* outp = qkv + (size_t)row0 * 128;
            #pragma unroll
            for (int it = 0; it < 2; ++it) {
                int tr = it * 32 + (tid >> 4), dv0 = (tid & 15) * 8;
                *(uint4*)&outp[tr * 128 + dv0] = *(const uint4*)&ts[tr][dv0];
            }
        }
        {
            unsigned short* kimg = qkv + K_OFF + ((size_t)(bq * 64 + s) * 2) * 4096;
            int region = tid >> 6, slot = tid & 63;
            int row = (region >> 1) * 16 + (slot & 15);
            int d = 128 + (region & 1) * 32 + (slot >> 4) * 8;
            uint4 vv = *(const uint4*)&ts[row][d];
            *(uint4*)&kimg[(region * 64 + slot) * 8] = vv;
        }
    } else {
        {
            unsigned short* kimg = qkv + K_OFF + ((size_t)(bq * 64 + s) * 2 + 1) * 4096;
            int region = tid >> 6, slot = tid & 63;
            int row = (region >> 1) * 16 + (slot & 15);
            int d = (region & 1) * 32 + (slot >> 4) * 8;
            uint4 vv = *(const uint4*)&ts[row][d];
            *(uint4*)&kimg[(region * 64 + slot) * 8] = vv;
        }
        {
            unsigned short* vimg = qkv + VT_OFF + (size_t)(bq * 64 + s) * 8192;
            #pragma unroll
            for (int it = 0; it < 2; ++it) {
                int lin = it * 512 + tid;
                int region = lin >> 6, slot = lin & 63;
                int dv = 64 + (region >> 1) * 16 + (slot & 15);
                int kv0 = (region & 1) * 32 + (slot >> 4) * 8;
                unsigned short tmp[8];
                #pragma unroll
                for (int e = 0; e < 8; ++e) tmp[e] = ts[kv0 + e][dv];
                *(uint4*)&vimg[(region * 64 + slot) * 8] = *(uint4*)tmp;
            }
        }
    }
}

// ---------------- Differential causal flash attention, fixed-size chunks ----------------
// grid (32, 4, 2*nc): z = c*2+branch, nc = 64>>chs chunks of EXACTLY (1<<chs)
// kv-tiles (chs=3 -> 8-tile chunks, 16 z-slices). Block c of pair
// (t_e=62-2bxe, t_o=63-2bxe) covers [c<<chs, min(n, (c+1)<<chs)); out-of-range
// blocks exit instantly. COMPLEMENT SWIZZLE bxe=(c&1)?31-bx:bx -> each CU gets
// 4-5 equal-duration live blocks (totals 32-34 tiles), ALL co-resident
// (LDS 32KB -> 5 blocks/CU) -> serial depth ~8 tile-latencies (was ~16).
// Body: fused QK (1 kf read -> 2 MFMA), ksf dbuf, 2 barriers/tile, V in regs.
// Records written iff (c<<chs) <= t; combine skips others.
__global__ __launch_bounds__(256, 5) void diff_attn_pair(
    const unsigned short* __restrict__ q, const unsigned short* __restrict__ kimg,
    const unsigned short* __restrict__ vimg,
    float* __restrict__ part, int chs) {
    const int bx = blockIdx.x, b = blockIdx.y;
    const int c = blockIdx.z >> 1, branch = blockIdx.z & 1;
    const int bxe = (c & 1) ? (31 - bx) : bx;
    const int t_o = 63 - 2 * bxe, t_e = t_o - 1;
    const int n = t_o + 1;
    const int s_lo = c << chs;
    if (s_lo >= n) return;  // dead chunk
    const int smax = min(n, s_lo + (1 << chs));

    const int tid = threadIdx.x;
    const int l = tid & 63, w = tid >> 6;
    const int gq = l >> 4, i16 = l & 15;
    const float NEGINF = -__builtin_inff();

    __shared__ unsigned short ksf[2][4096];  // 16 KB K frag image, dbuf
    __shared__ unsigned short psf[8192];     // 16 KB P (both qsets)

    const int rshift = 6 - chs;  // record slots per (b,t)
    float* recA = part + ((((size_t)(b * 64 + t_e) << rshift) + c) * 2 + branch) * REC_FLOATS;
    float* recB = part + ((((size_t)(b * 64 + t_o) << rshift) + c) * 2 + branch) * REC_FLOATS;
    const bool emptyA = (s_lo > t_e);

    const size_t bbase = (size_t)b * 4096;
    const unsigned short* kimg_b = kimg + (size_t)b * 524288;
    const unsigned short* vimg_b = vimg + (size_t)b * 524288;
    const int tid8 = tid * 8;
    const int l8 = l * 8;
    const f32x4 z4 = {0.f, 0.f, 0.f, 0.f};

    bf16x8 qfA[2], qfB[2];
    #pragma unroll
    for (int cc = 0; cc < 2; ++cc) {
        qfA[cc] = *(const bf16x8*)&q[(bbase + t_e * 64 + w * 16 + i16) * 128 + branch * 64 + cc * 32 + 8 * gq];
        qfB[cc] = *(const bf16x8*)&q[(bbase + t_o * 64 + w * 16 + i16) * 128 + branch * 64 + cc * 32 + 8 * gq];
    }

    float lsumA = 0.f, lsumB = 0.f;
    f32x4 acc[2][4][2];
    for (int qs = 0; qs < 2; ++qs)
        for (int qg = 0; qg < 4; ++qg)
            for (int j = 0; j < 2; ++j) acc[qs][qg][j] = z4;

    int pdst[4];
    #pragma unroll
    for (int cb = 0; cb < 4; ++cb)
        pdst[cb] = ((w * 2 + (cb >> 1)) * 64 + ((cb & 1) * 2 + (gq >> 1)) * 16 + i16) * 8 + (gq & 1) * 4;

    uint4 kr0, kr1;
    bf16x8 vb00, vb01, vb10, vb11;

#define K_ISSUE(s_) do {                                                            \
        const unsigned short* kp = &kimg_b[((size_t)(s_) * 2 + branch) * 4096];     \
        kr0 = *(const uint4*)&kp[tid8];                                             \
        kr1 = *(const uint4*)&kp[tid8 + 2048];                                      \
    } while (0)
#define V_ISSUE(s_) do {                                                            \
        const unsigned short* vp = &vimg_b[(size_t)(s_) * 8192 + w * 2048];         \
        vb00 = *(const bf16x8*)&vp[l8];                                             \
        vb01 = *(const bf16x8*)&vp[512 + l8];                                       \
        vb10 = *(const bf16x8*)&vp[1024 + l8];                                      \
        vb11 = *(const bf16x8*)&vp[1536 + l8];                                      \
    } while (0)

    K_ISSUE(s_lo);
    V_ISSUE(s_lo);
    int pb = 0;
    #pragma unroll 1
    for (int s = s_lo; s < smax; ++s) {
        *(uint4*)&ksf[pb][tid8] = kr0;
        *(uint4*)&ksf[pb][tid8 + 2048] = kr1;
        if (s + 1 < smax) K_ISSUE(s + 1);
        __syncthreads();   // merged: ksf[pb] ready + prev PV done reading psf
        const bool aAct = (s != t_o);

        f32x4 scA[4], scB[4];
        for (int cb = 0; cb < 4; ++cb) { scA[cb] = z4; scB[cb] = z4; }
        __builtin_amdgcn_s_setprio(1);
        #pragma unroll
        for (int cb = 0; cb < 4; ++cb)
            for (int cc = 0; cc < 2; ++cc) {
                bf16x8 kf = *(const bf16x8*)&ksf[pb][((cb * 2 + cc) * 64 + l) * 8];
                scA[cb] = __builtin_amdgcn_mfma_f32_16x16x32_bf16(kf, qfA[cc], scA[cb], 0, 0, 0);
                scB[cb] = __builtin_amdgcn_mfma_f32_16x16x32_bf16(kf, qfB[cc], scB[cb], 0, 0, 0);
            }
        __builtin_amdgcn_s_setprio(0);

        if (aAct) {
            if (s == t_e) {
                int ql = w * 16 + i16;
                for (int cb = 0; cb < 4; ++cb)
                    for (int r = 0; r < 4; ++r)
                        if (cb * 16 + gq * 4 + r > ql) scA[cb][r] = NEGINF;
            }
            #pragma unroll
            for (int cb = 0; cb < 4; ++cb) {
                float p0 = exp2f(scA[cb][0]);
                float p1 = exp2f(scA[cb][1]);
                float p2 = exp2f(scA[cb][2]);
                float p3 = exp2f(scA[cb][3]);
                lsumA += (p0 + p1) + (p2 + p3);
                uint2 pw;
                pw.x = cvt_pk_bf16(p0, p1);
                pw.y = cvt_pk_bf16(p2, p3);
                *(uint2*)&psf[pdst[cb]] = pw;
            }
        }
        {
            if (s == t_o) {
                int ql = w * 16 + i16;
                for (int cb = 0; cb < 4; ++cb)
                    for (int r = 0; r < 4; ++r)
                        if (cb * 16 + gq * 4 + r > ql) scB[cb][r] = NEGINF;
            }
            #pragma unroll
            for (int cb = 0; cb < 4; ++cb) {
                float p0 = exp2f(scB[cb][0]);
                float p1 = exp2f(scB[cb][1]);
                float p2 = exp2f(scB[cb][2]);
                float p3 = exp2f(scB[cb][3]);
                lsumB += (p0 + p1) + (p2 + p3);
                uint2 pw;
                pw.x = cvt_pk_bf16(p0, p1);
                pw.y = cvt_pk_bf16(p2, p3);
                *(uint2*)&psf[4096 + pdst[cb]] = pw;
            }
        }
        __syncthreads();   // psf complete

        __builtin_amdgcn_s_setprio(1);
        if (aAct) {
            #pragma unroll
            for (int qg = 0; qg < 4; ++qg) {
                bf16x8 pa0 = *(const bf16x8*)&psf[(qg * 2 + 0) * 512 + l8];
                bf16x8 pa1 = *(const bf16x8*)&psf[(qg * 2 + 1) * 512 + l8];
                acc[0][qg][0] = __builtin_amdgcn_mfma_f32_16x16x32_bf16(pa0, vb00, acc[0][qg][0], 0, 0, 0);
                acc[0][qg][0] = __builtin_amdgcn_mfma_f32_16x16x32_bf16(pa1, vb01, acc[0][qg][0], 0, 0, 0);
                acc[0][qg][1] = __builtin_amdgcn_mfma_f32_16x16x32_bf16(pa0, vb10, acc[0][qg][1], 0, 0, 0);
                acc[0][qg][1] = __builtin_amdgcn_mfma_f32_16x16x32_bf16(pa1, vb11, acc[0][qg][1], 0, 0, 0);
            }
        }
        #pragma unroll
        for (int qg = 0; qg < 4; ++qg) {
            bf16x8 pa0 = *(const bf16x8*)&psf[4096 + (qg * 2 + 0) * 512 + l8];
            bf16x8 pa1 = *(const bf16x8*)&psf[4096 + (qg * 2 + 1) * 512 + l8];
            acc[1][qg][0] = __builtin_amdgcn_mfma_f32_16x16x32_bf16(pa0, vb00, acc[1][qg][0], 0, 0, 0);
            acc[1][qg][0] = __builtin_amdgcn_mfma_f32_16x16x32_bf16(pa1, vb01, acc[1][qg][0], 0, 0, 0);
            acc[1][qg][1] = __builtin_amdgcn_mfma_f32_16x16x32_bf16(pa0, vb10, acc[1][qg][1], 0, 0, 0);
            acc[1][qg][1] = __builtin_amdgcn_mfma_f32_16x16x32_bf16(pa1, vb11, acc[1][qg][1], 0, 0, 0);
        }
        __builtin_amdgcn_s_setprio(0);
        if (s + 1 < smax) V_ISSUE(s + 1);
        pb ^= 1;
    }
#undef K_ISSUE
#undef V_ISSUE

    lsumA += __shfl_xor(lsumA, 16);
    lsumA += __shfl_xor(lsumA, 32);
    lsumB += __shfl_xor(lsumB, 16);
    lsumB += __shfl_xor(lsumB, 32);
    if (!emptyA) {
        if (gq == 0) recA[w * 16 + i16] = lsumA;
        unsigned short* OA = (unsigned short*)(recA + 64);
        for (int qg = 0; qg < 4; ++qg)
            for (int j = 0; j < 2; ++j)
                for (int r = 0; r < 4; ++r)
                    OA[(qg * 16 + gq * 4 + r) * 128 + (w * 2 + j) * 16 + i16] = f2bf(acc[0][qg][j][r]);
    }
    {
        if (gq == 0) recB[w * 16 + i16] = lsumB;
        unsigned short* OB = (unsigned short*)(recB + 64);
        for (int qg = 0; qg < 4; ++qg)
            for (int j = 0; j < 2; ++j)
                for (int r = 0; r < 4; ++r)
                    OB[(qg * 16 + gq * 4 + r) * 128 + (w * 2 + j) * 16 + i16] = f2bf(acc[1][qg][j][r]);
    }
}

// ---------------- combine: sum valid chunks per branch, normalize, o1 - lam*o2 ----------
__global__ __launch_bounds__(256) void diff_combine(
    const float* __restrict__ part,
    const float* __restrict__ lq1, const float* __restrict__ lq2,
    const float* __restrict__ lk1, const float* __restrict__ lk2,
    float* __restrict__ out, int chs) {
    const int t = blockIdx.x, b = blockIdx.y;
    const int tid = threadIdx.x;
    const int nc = 64 >> chs;
    const int rshift = 6 - chs;
    __shared__ float sl[2][64];
    __shared__ float s_lam;

    const float* recbase = part + ((size_t)(b * 64 + t) << rshift) * 2 * REC_FLOATS;

    if (tid < 64) {
        float s1 = lq1[tid] * lk1[tid];
        float s2 = lq2[tid] * lk2[tid];
        for (int off = 32; off > 0; off >>= 1) {
            s1 += __shfl_xor(s1, off);
            s2 += __shfl_xor(s2, off);
        }
        if (tid == 0) s_lam = expf(s1) - expf(s2) + LAMBDA_INIT;
    }
    if (tid < 128) {
        int r = tid & 63, br = tid >> 6;
        float acc = 0.f;
        for (int c = 0; c < nc; ++c) {
            if ((c << chs) > t) break;  // chunk has no record for this row
            acc += recbase[(c * 2 + br) * REC_FLOATS + r];
        }
        sl[br][r] = acc;
    }
    __syncthreads();
    const float lam = s_lam;

    float* op = out + ((size_t)b * 4096 + (size_t)t * 64) * 128;
    for (int grp = 0; grp < 4; ++grp) {
        int gid = grp * 256 + tid;
        int e = gid * 8;
        int row = e >> 7;
        float o1[8] = {0, 0, 0, 0, 0, 0, 0, 0}, o2[8] = {0, 0, 0, 0, 0, 0, 0, 0};
        for (int c = 0; c < nc; ++c) {
            if ((c << chs) > t) break;
            const unsigned short* O0 = (const unsigned short*)(recbase + (c * 2 + 0) * REC_FLOATS + 64);
            const unsigned short* O1 = (const unsigned short*)(recbase + (c * 2 + 1) * REC_FLOATS + 64);
            uint4 u0 = *(const uint4*)&O0[e];
            uint4 u1 = *(const uint4*)&O1[e];
            const unsigned short* e0 = (const unsigned short*)&u0;
            const unsigned short* e1 = (const unsigned short*)&u1;
            #pragma unroll
            for (int j = 0; j < 8; ++j) {
                o1[j] += bf2f(e0[j]);
                o2[j] += bf2f(e1[j]);
            }
        }
        float l1inv = 1.0f / sl[0][row], l2inv = 1.0f / sl[1][row];
        float res[8];
        #pragma unroll
        for (int j = 0; j < 8; ++j) res[j] = o1[j] * l1inv - lam * o2[j] * l2inv;
        *(float4*)&op[e] = *(float4*)&res[0];
        *(float4*)&op[e + 4] = *(float4*)&res[4];
    }
}

extern "C" void kernel_launch(void* const* d_in, const int* in_sizes, int n_in,
                              void* d_out, int out_size, void* d_ws, size_t ws_size,
                              hipStream_t stream) {
    const float* x   = (const float*)d_in[0];
    const float* Wq  = (const float*)d_in[1];
    const float* Wk  = (const float*)d_in[2];
    const float* Wv  = (const float*)d_in[3];
    const float* lq1 = (const float*)d_in[4];
    const float* lq2 = (const float*)d_in[5];
    const float* lk1 = (const float*)d_in[6];
    const float* lk2 = (const float*)d_in[7];
    float* out = (float*)d_out;
    unsigned short* qkv = (unsigned short*)d_ws;

    // chunk size 8 tiles (chs=3, 8 record slots) if ws fits; else 16 (chs=4)
    const size_t WT_BYTES = (size_t)384 * 1024 * 2;
    int chs = 4;
    {
        size_t part8 = (size_t)256 * 8 * 2 * REC_FLOATS * 4;
        if (ws_size >= PART_OFF_BYTES + part8 + WT_BYTES) chs = 3;
    }
    const size_t part_bytes = (size_t)256 * (64 >> chs) * 2 * REC_FLOATS * 4;
    float* part = (float*)((char*)d_ws + PART_OFF_BYTES);
    unsigned short* WT = (unsigned short*)((char*)d_ws + PART_OFF_BYTES + part_bytes);

    prep_wt<<<dim3(16, 2, 3), 256, 0, stream>>>(Wq, Wk, Wv, WT);
    qkv_fused<<<dim3(256, 2), 512, 0, stream>>>(x, WT, qkv);

    const unsigned short* qb = qkv;
    const unsigned short* kb = qkv + K_OFF;
    const unsigned short* vtb = qkv + VT_OFF;
    diff_attn_pair<<<dim3(32, 4, 2 * (64 >> chs)), 256, 0, stream>>>(qb, kb, vtb, part, chs);
    diff_combine<<<dim3(64, 4), 256, 0, stream>>>(part, lq1, lq2, lk1, lk2, out, chs);
}

// Round 21
// 158.646 us; speedup vs baseline: 1.6419x; 1.6419x over previous
//
#include <hip/hip_runtime.h>
#include <hip/hip_bf16.h>

typedef __bf16 bf16x8 __attribute__((ext_vector_type(8)));
typedef float f32x4 __attribute__((ext_vector_type(4)));

#define LAMBDA_INIT 0.3555090675909693f
#define CEXP 0.18033688011112042f   // 0.125 * log2(e), folded into Q at projection

// ws layout (bytes):
//  q    : [0, 4.19M)       bf16 [16384][128] row-major, PRE-SCALED by CEXP
//  kimg : [4.19M, 8.39M)   bf16 [4][64][2][8 regions][64 slots][8]  (frag image)
//  vimg : [8.39M, 12.58M)  bf16 [4][64][16 regions][64 slots][8]    (frag image)
//  part : [12.58M, +68.2M) recs x 16640B (l[64] f32 + O[64][128] bf16), 8 slots/(b,t)
//  WT   : after part       bf16 W'[384][1024]
#define K_OFF   ((size_t)16384 * 128)
#define VT_OFF  ((size_t)2 * 16384 * 128)
#define PART_OFF_BYTES ((size_t)12582912)
#define REC_FLOATS 4160  // 64 l + 4096 words of bf16 O

__device__ __forceinline__ unsigned short f2bf(float f) {
    __hip_bfloat16 h = __float2bfloat16(f);
    unsigned short u;
    __builtin_memcpy(&u, &h, 2);
    return u;
}
__device__ __forceinline__ float bf2f(unsigned short u) {
    unsigned int x = ((unsigned int)u) << 16;
    float f;
    __builtin_memcpy(&f, &x, 4);
    return f;
}
__device__ __forceinline__ unsigned int cvt_pk_bf16(float a, float b) {
    unsigned int r;
    asm volatile("v_cvt_pk_bf16_f32 %0, %1, %2" : "=v"(r) : "v"(a), "v"(b));
    return r;
}

// ---------------- W pre-transpose: [1024][128] f32 -> [128][1024] bf16 ----------------
__global__ __launch_bounds__(256) void prep_wt(
    const float* __restrict__ Wq, const float* __restrict__ Wk,
    const float* __restrict__ Wv, unsigned short* __restrict__ WT) {
    const int kt = blockIdx.x, nt = blockIdx.y, mat = blockIdx.z;
    const float* W = (mat == 0) ? Wq : (mat == 1) ? Wk : Wv;
    unsigned short* O = WT + (size_t)mat * 128 * 1024;
    __shared__ float tb[64][65];
    const int r = threadIdx.x >> 2, c4 = (threadIdx.x & 3) * 16;
    for (int j = 0; j < 4; ++j) {
        float4 v = *(const float4*)&W[(size_t)(kt * 64 + r) * 128 + nt * 64 + c4 + j * 4];
        tb[r][c4 + j * 4 + 0] = v.x;
        tb[r][c4 + j * 4 + 1] = v.y;
        tb[r][c4 + j * 4 + 2] = v.z;
        tb[r][c4 + j * 4 + 3] = v.w;
    }
    __syncthreads();
    unsigned short tmp[16];
    for (int j = 0; j < 16; ++j) tmp[j] = f2bf(tb[c4 + j][r]);
    *(uint4*)&O[(size_t)(nt * 64 + r) * 1024 + kt * 64 + c4] = *(uint4*)&tmp[0];
    *(uint4*)&O[(size_t)(nt * 64 + r) * 1024 + kt * 64 + c4 + 8] = *(uint4*)&tmp[8];
}

// ---------------- Fused QKV GEMM, N-split: grid (256 row-tiles, 2 N-halves) ----------
__global__ __launch_bounds__(512) void qkv_fused(
    const float* __restrict__ x, const unsigned short* __restrict__ WT,
    unsigned short* __restrict__ qkv) {
    const int tid = threadIdx.x;
    const int l = tid & 63, w = tid >> 6;
    const int g = l >> 4, i16 = l & 15;
    const int rh = w >> 2, cp = w & 3;
    const int row0 = blockIdx.x * 64;
    const int np = blockIdx.y;
    const unsigned short* Wt = WT + (size_t)np * 192 * 1024;

    __shared__ unsigned short xs[64][72];
    __shared__ unsigned short wt[192][72];

    f32x4 acc[2][3];
    const f32x4 z4 = {0.f, 0.f, 0.f, 0.f};
    for (int rt = 0; rt < 2; ++rt)
        for (int ct = 0; ct < 3; ++ct) acc[rt][ct] = z4;

    const int xrow = tid >> 3, xcol = (tid & 7) * 8;
    const int wn = tid >> 3, wk8 = (tid & 7) * 8;
    const float* xp = &x[(size_t)(row0 + xrow) * 1024 + xcol];
    const unsigned short* wp = &Wt[(size_t)wn * 1024 + wk8];

    float4 ax0, ax1;
    uint4 aw0, aw1, aw2;

#define QI(k0_) do {                                                        \
        ax0 = *(const float4*)&xp[(k0_)];                                   \
        ax1 = *(const float4*)&xp[(k0_) + 4];                               \
        aw0 = *(const uint4*)&wp[(k0_)];                                    \
        aw1 = *(const uint4*)&wp[64 * 1024 + (k0_)];                        \
        aw2 = *(const uint4*)&wp[128 * 1024 + (k0_)];                       \
    } while (0)

#define QS() do {                                                           \
        *(ushort4*)&xs[xrow][xcol]     = make_ushort4(f2bf(ax0.x), f2bf(ax0.y), f2bf(ax0.z), f2bf(ax0.w)); \
        *(ushort4*)&xs[xrow][xcol + 4] = make_ushort4(f2bf(ax1.x), f2bf(ax1.y), f2bf(ax1.z), f2bf(ax1.w)); \
        *(uint4*)&wt[wn +   0][wk8] = aw0;                                  \
        *(uint4*)&wt[wn +  64][wk8] = aw1;                                  \
        *(uint4*)&wt[wn + 128][wk8] = aw2;                                  \
    } while (0)

    QI(0);
    #pragma unroll 1
    for (int k0 = 0; k0 < 1024; k0 += 64) {
        __syncthreads();
        QS();
        if (k0 + 64 < 1024) QI(k0 + 64);
        __syncthreads();
        bf16x8 af[2][2];
        #pragma unroll
        for (int rt = 0; rt < 2; ++rt)
            for (int cc = 0; cc < 2; ++cc)
                af[rt][cc] = *(const bf16x8*)&xs[rh * 32 + rt * 16 + i16][cc * 32 + 8 * g];
        #pragma unroll
        for (int ct = 0; ct < 3; ++ct)
            for (int cc = 0; cc < 2; ++cc) {
                bf16x8 bb = *(const bf16x8*)&wt[cp * 48 + ct * 16 + i16][cc * 32 + 8 * g];
                for (int rt = 0; rt < 2; ++rt)
                    acc[rt][ct] = __builtin_amdgcn_mfma_f32_16x16x32_bf16(af[rt][cc], bb, acc[rt][ct], 0, 0, 0);
            }
    }
#undef QI
#undef QS

    __syncthreads();
    unsigned short(*ts)[200] = (unsigned short(*)[200]) & wt[0][0];
    #pragma unroll
    for (int rt = 0; rt < 2; ++rt)
        for (int ct = 0; ct < 3; ++ct) {
            const float sc = (np == 0 && cp * 48 + ct * 16 < 128) ? CEXP : 1.0f;
            for (int r = 0; r < 4; ++r)
                ts[rh * 32 + rt * 16 + g * 4 + r][cp * 48 + ct * 16 + i16] = f2bf(acc[rt][ct][r] * sc);
        }
    __syncthreads();

    const int bq = row0 >> 12;
    const int s = (row0 >> 6) & 63;
    if (np == 0) {
        {
            unsigned short* outp = qkv + (size_t)row0 * 128;
            #pragma unroll
            for (int it = 0; it < 2; ++it) {
                int tr = it * 32 + (tid >> 4), dv0 = (tid & 15) * 8;
                *(uint4*)&outp[tr * 128 + dv0] = *(const uint4*)&ts[tr][dv0];
            }
        }
        {
            unsigned short* kimg = qkv + K_OFF + ((size_t)(bq * 64 + s) * 2) * 4096;
            int region = tid >> 6, slot = tid & 63;
            int row = (region >> 1) * 16 + (slot & 15);
            int d = 128 + (region & 1) * 32 + (slot >> 4) * 8;
            uint4 vv = *(const uint4*)&ts[row][d];
            *(uint4*)&kimg[(region * 64 + slot) * 8] = vv;
        }
    } else {
        {
            unsigned short* kimg = qkv + K_OFF + ((size_t)(bq * 64 + s) * 2 + 1) * 4096;
            int region = tid >> 6, slot = tid & 63;
            int row = (region >> 1) * 16 + (slot & 15);
            int d = (region & 1) * 32 + (slot >> 4) * 8;
            uint4 vv = *(const uint4*)&ts[row][d];
            *(uint4*)&kimg[(region * 64 + slot) * 8] = vv;
        }
        {
            unsigned short* vimg = qkv + VT_OFF + (size_t)(bq * 64 + s) * 8192;
            #pragma unroll
            for (int it = 0; it < 2; ++it) {
                int lin = it * 512 + tid;
                int region = lin >> 6, slot = lin & 63;
                int dv = 64 + (region >> 1) * 16 + (slot & 15);
                int kv0 = (region & 1) * 32 + (slot >> 4) * 8;
                unsigned short tmp[8];
                #pragma unroll
                for (int e = 0; e < 8; ++e) tmp[e] = ts[kv0 + e][dv];
                *(uint4*)&vimg[(region * 64 + slot) * 8] = *(uint4*)tmp;
            }
        }
    }
}

// ---------------- Differential causal flash attention, fixed-size chunks ----------------
// grid (32, 4, 2*nc): z = c*2+branch, nc = 64>>chs chunks of EXACTLY (1<<chs)
// kv-tiles. Block c of pair (t_e=62-2bxe, t_o=63-2bxe) covers
// [c<<chs, min(n,(c+1)<<chs)); dead chunks exit instantly. COMPLEMENT SWIZZLE
// bxe=(c&1)?31-bx:bx -> each CU gets 4-5 equal-duration live blocks (32-34
// tiles total), co-resident -> serial depth ~8-9 tile-latencies (was ~16).
// __launch_bounds__(256,4): VGPR cap 128 >= natural 84 -> NO SPILL (the (256,5)
// build spilled acc to scratch: 48 VGPR, 519MB writes, 228us).
// Body: fused QK, ksf dbuf, 2 barriers/tile, V in regs. LDS 32KB.
__global__ __launch_bounds__(256, 4) void diff_attn_pair(
    const unsigned short* __restrict__ q, const unsigned short* __restrict__ kimg,
    const unsigned short* __restrict__ vimg,
    float* __restrict__ part, int chs) {
    const int bx = blockIdx.x, b = blockIdx.y;
    const int c = blockIdx.z >> 1, branch = blockIdx.z & 1;
    const int bxe = (c & 1) ? (31 - bx) : bx;
    const int t_o = 63 - 2 * bxe, t_e = t_o - 1;
    const int n = t_o + 1;
    const int s_lo = c << chs;
    if (s_lo >= n) return;  // dead chunk
    const int smax = min(n, s_lo + (1 << chs));

    const int tid = threadIdx.x;
    const int l = tid & 63, w = tid >> 6;
    const int gq = l >> 4, i16 = l & 15;
    const float NEGINF = -__builtin_inff();

    __shared__ unsigned short ksf[2][4096];  // 16 KB K frag image, dbuf
    __shared__ unsigned short psf[8192];     // 16 KB P (both qsets)

    const int rshift = 6 - chs;  // record slots per (b,t)
    float* recA = part + ((((size_t)(b * 64 + t_e) << rshift) + c) * 2 + branch) * REC_FLOATS;
    float* recB = part + ((((size_t)(b * 64 + t_o) << rshift) + c) * 2 + branch) * REC_FLOATS;
    const bool emptyA = (s_lo > t_e);

    const size_t bbase = (size_t)b * 4096;
    const unsigned short* kimg_b = kimg + (size_t)b * 524288;
    const unsigned short* vimg_b = vimg + (size_t)b * 524288;
    const int tid8 = tid * 8;
    const int l8 = l * 8;
    const f32x4 z4 = {0.f, 0.f, 0.f, 0.f};

    bf16x8 qfA[2], qfB[2];
    #pragma unroll
    for (int cc = 0; cc < 2; ++cc) {
        qfA[cc] = *(const bf16x8*)&q[(bbase + t_e * 64 + w * 16 + i16) * 128 + branch * 64 + cc * 32 + 8 * gq];
        qfB[cc] = *(const bf16x8*)&q[(bbase + t_o * 64 + w * 16 + i16) * 128 + branch * 64 + cc * 32 + 8 * gq];
    }

    float lsumA = 0.f, lsumB = 0.f;
    f32x4 acc[2][4][2];
    for (int qs = 0; qs < 2; ++qs)
        for (int qg = 0; qg < 4; ++qg)
            for (int j = 0; j < 2; ++j) acc[qs][qg][j] = z4;

    int pdst[4];
    #pragma unroll
    for (int cb = 0; cb < 4; ++cb)
        pdst[cb] = ((w * 2 + (cb >> 1)) * 64 + ((cb & 1) * 2 + (gq >> 1)) * 16 + i16) * 8 + (gq & 1) * 4;

    uint4 kr0, kr1;
    bf16x8 vb00, vb01, vb10, vb11;

#define K_ISSUE(s_) do {                                                            \
        const unsigned short* kp = &kimg_b[((size_t)(s_) * 2 + branch) * 4096];     \
        kr0 = *(const uint4*)&kp[tid8];                                             \
        kr1 = *(const uint4*)&kp[tid8 + 2048];                                      \
    } while (0)
#define V_ISSUE(s_) do {                                                            \
        const unsigned short* vp = &vimg_b[(size_t)(s_) * 8192 + w * 2048];         \
        vb00 = *(const bf16x8*)&vp[l8];                                             \
        vb01 = *(const bf16x8*)&vp[512 + l8];                                       \
        vb10 = *(const bf16x8*)&vp[1024 + l8];                                      \
        vb11 = *(const bf16x8*)&vp[1536 + l8];                                      \
    } while (0)

    K_ISSUE(s_lo);
    V_ISSUE(s_lo);
    int pb = 0;
    #pragma unroll 1
    for (int s = s_lo; s < smax; ++s) {
        *(uint4*)&ksf[pb][tid8] = kr0;
        *(uint4*)&ksf[pb][tid8 + 2048] = kr1;
        if (s + 1 < smax) K_ISSUE(s + 1);
        __syncthreads();   // merged: ksf[pb] ready + prev PV done reading psf
        const bool aAct = (s != t_o);

        f32x4 scA[4], scB[4];
        for (int cb = 0; cb < 4; ++cb) { scA[cb] = z4; scB[cb] = z4; }
        __builtin_amdgcn_s_setprio(1);
        #pragma unroll
        for (int cb = 0; cb < 4; ++cb)
            for (int cc = 0; cc < 2; ++cc) {
                bf16x8 kf = *(const bf16x8*)&ksf[pb][((cb * 2 + cc) * 64 + l) * 8];
                scA[cb] = __builtin_amdgcn_mfma_f32_16x16x32_bf16(kf, qfA[cc], scA[cb], 0, 0, 0);
                scB[cb] = __builtin_amdgcn_mfma_f32_16x16x32_bf16(kf, qfB[cc], scB[cb], 0, 0, 0);
            }
        __builtin_amdgcn_s_setprio(0);

        if (aAct) {
            if (s == t_e) {
                int ql = w * 16 + i16;
                for (int cb = 0; cb < 4; ++cb)
                    for (int r = 0; r < 4; ++r)
                        if (cb * 16 + gq * 4 + r > ql) scA[cb][r] = NEGINF;
            }
            #pragma unroll
            for (int cb = 0; cb < 4; ++cb) {
                float p0 = exp2f(scA[cb][0]);
                float p1 = exp2f(scA[cb][1]);
                float p2 = exp2f(scA[cb][2]);
                float p3 = exp2f(scA[cb][3]);
                lsumA += (p0 + p1) + (p2 + p3);
                uint2 pw;
                pw.x = cvt_pk_bf16(p0, p1);
                pw.y = cvt_pk_bf16(p2, p3);
                *(uint2*)&psf[pdst[cb]] = pw;
            }
        }
        {
            if (s == t_o) {
                int ql = w * 16 + i16;
                for (int cb = 0; cb < 4; ++cb)
                    for (int r = 0; r < 4; ++r)
                        if (cb * 16 + gq * 4 + r > ql) scB[cb][r] = NEGINF;
            }
            #pragma unroll
            for (int cb = 0; cb < 4; ++cb) {
                float p0 = exp2f(scB[cb][0]);
                float p1 = exp2f(scB[cb][1]);
                float p2 = exp2f(scB[cb][2]);
                float p3 = exp2f(scB[cb][3]);
                lsumB += (p0 + p1) + (p2 + p3);
                uint2 pw;
                pw.x = cvt_pk_bf16(p0, p1);
                pw.y = cvt_pk_bf16(p2, p3);
                *(uint2*)&psf[4096 + pdst[cb]] = pw;
            }
        }
        __syncthreads();   // psf complete

        __builtin_amdgcn_s_setprio(1);
        if (aAct) {
            #pragma unroll
            for (int qg = 0; qg < 4; ++qg) {
                bf16x8 pa0 = *(const bf16x8*)&psf[(qg * 2 + 0) * 512 + l8];
                bf16x8 pa1 = *(const bf16x8*)&psf[(qg * 2 + 1) * 512 + l8];
                acc[0][qg][0] = __builtin_amdgcn_mfma_f32_16x16x32_bf16(pa0, vb00, acc[0][qg][0], 0, 0, 0);
                acc[0][qg][0] = __builtin_amdgcn_mfma_f32_16x16x32_bf16(pa1, vb01, acc[0][qg][0], 0, 0, 0);
                acc[0][qg][1] = __builtin_amdgcn_mfma_f32_16x16x32_bf16(pa0, vb10, acc[0][qg][1], 0, 0, 0);
                acc[0][qg][1] = __builtin_amdgcn_mfma_f32_16x16x32_bf16(pa1, vb11, acc[0][qg][1], 0, 0, 0);
            }
        }
        #pragma unroll
        for (int qg = 0; qg < 4; ++qg) {
            bf16x8 pa0 = *(const bf16x8*)&psf[4096 + (qg * 2 + 0) * 512 + l8];
            bf16x8 pa1 = *(const bf16x8*)&psf[4096 + (qg * 2 + 1) * 512 + l8];
            acc[1][qg][0] = __builtin_amdgcn_mfma_f32_16x16x32_bf16(pa0, vb00, acc[1][qg][0], 0, 0, 0);
            acc[1][qg][0] = __builtin_amdgcn_mfma_f32_16x16x32_bf16(pa1, vb01, acc[1][qg][0], 0, 0, 0);
            acc[1][qg][1] = __builtin_amdgcn_mfma_f32_16x16x32_bf16(pa0, vb10, acc[1][qg][1], 0, 0, 0);
            acc[1][qg][1] = __builtin_amdgcn_mfma_f32_16x16x32_bf16(pa1, vb11, acc[1][qg][1], 0, 0, 0);
        }
        __builtin_amdgcn_s_setprio(0);
        if (s + 1 < smax) V_ISSUE(s + 1);
        pb ^= 1;
    }
#undef K_ISSUE
#undef V_ISSUE

    lsumA += __shfl_xor(lsumA, 16);
    lsumA += __shfl_xor(lsumA, 32);
    lsumB += __shfl_xor(lsumB, 16);
    lsumB += __shfl_xor(lsumB, 32);
    if (!emptyA) {
        if (gq == 0) recA[w * 16 + i16] = lsumA;
        unsigned short* OA = (unsigned short*)(recA + 64);
        for (int qg = 0; qg < 4; ++qg)
            for (int j = 0; j < 2; ++j)
                for (int r = 0; r < 4; ++r)
                    OA[(qg * 16 + gq * 4 + r) * 128 + (w * 2 + j) * 16 + i16] = f2bf(acc[0][qg][j][r]);
    }
    {
        if (gq == 0) recB[w * 16 + i16] = lsumB;
        unsigned short* OB = (unsigned short*)(recB + 64);
        for (int qg = 0; qg < 4; ++qg)
            for (int j = 0; j < 2; ++j)
                for (int r = 0; r < 4; ++r)
                    OB[(qg * 16 + gq * 4 + r) * 128 + (w * 2 + j) * 16 + i16] = f2bf(acc[1][qg][j][r]);
    }
}

// ---------------- combine: sum valid chunks per branch, normalize, o1 - lam*o2 ----------
__global__ __launch_bounds__(256) void diff_combine(
    const float* __restrict__ part,
    const float* __restrict__ lq1, const float* __restrict__ lq2,
    const float* __restrict__ lk1, const float* __restrict__ lk2,
    float* __restrict__ out, int chs) {
    const int t = blockIdx.x, b = blockIdx.y;
    const int tid = threadIdx.x;
    const int nc = 64 >> chs;
    const int rshift = 6 - chs;
    __shared__ float sl[2][64];
    __shared__ float s_lam;

    const float* recbase = part + ((size_t)(b * 64 + t) << rshift) * 2 * REC_FLOATS;

    if (tid < 64) {
        float s1 = lq1[tid] * lk1[tid];
        float s2 = lq2[tid] * lk2[tid];
        for (int off = 32; off > 0; off >>= 1) {
            s1 += __shfl_xor(s1, off);
            s2 += __shfl_xor(s2, off);
        }
        if (tid == 0) s_lam = expf(s1) - expf(s2) + LAMBDA_INIT;
    }
    if (tid < 128) {
        int r = tid & 63, br = tid >> 6;
        float acc = 0.f;
        for (int c = 0; c < nc; ++c) {
            if ((c << chs) > t) break;
            acc += recbase[(c * 2 + br) * REC_FLOATS + r];
        }
        sl[br][r] = acc;
    }
    __syncthreads();
    const float lam = s_lam;

    float* op = out + ((size_t)b * 4096 + (size_t)t * 64) * 128;
    for (int grp = 0; grp < 4; ++grp) {
        int gid = grp * 256 + tid;
        int e = gid * 8;
        int row = e >> 7;
        float o1[8] = {0, 0, 0, 0, 0, 0, 0, 0}, o2[8] = {0, 0, 0, 0, 0, 0, 0, 0};
        for (int c = 0; c < nc; ++c) {
            if ((c << chs) > t) break;
            const unsigned short* O0 = (const unsigned short*)(recbase + (c * 2 + 0) * REC_FLOATS + 64);
            const unsigned short* O1 = (const unsigned short*)(recbase + (c * 2 + 1) * REC_FLOATS + 64);
            uint4 u0 = *(const uint4*)&O0[e];
            uint4 u1 = *(const uint4*)&O1[e];
            const unsigned short* e0 = (const unsigned short*)&u0;
            const unsigned short* e1 = (const unsigned short*)&u1;
            #pragma unroll
            for (int j = 0; j < 8; ++j) {
                o1[j] += bf2f(e0[j]);
                o2[j] += bf2f(e1[j]);
            }
        }
        float l1inv = 1.0f / sl[0][row], l2inv = 1.0f / sl[1][row];
        float res[8];
        #pragma unroll
        for (int j = 0; j < 8; ++j) res[j] = o1[j] * l1inv - lam * o2[j] * l2inv;
        *(float4*)&op[e] = *(float4*)&res[0];
        *(float4*)&op[e + 4] = *(float4*)&res[4];
    }
}

extern "C" void kernel_launch(void* const* d_in, const int* in_sizes, int n_in,
                              void* d_out, int out_size, void* d_ws, size_t ws_size,
                              hipStream_t stream) {
    const float* x   = (const float*)d_in[0];
    const float* Wq  = (const float*)d_in[1];
    const float* Wk  = (const float*)d_in[2];
    const float* Wv  = (const float*)d_in[3];
    const float* lq1 = (const float*)d_in[4];
    const float* lq2 = (const float*)d_in[5];
    const float* lk1 = (const float*)d_in[6];
    const float* lk2 = (const float*)d_in[7];
    float* out = (float*)d_out;
    unsigned short* qkv = (unsigned short*)d_ws;

    // chunk size 8 tiles (chs=3, 8 record slots) if ws fits; else 16 (chs=4)
    const size_t WT_BYTES = (size_t)384 * 1024 * 2;
    int chs = 4;
    {
        size_t part8 = (size_t)256 * 8 * 2 * REC_FLOATS * 4;
        if (ws_size >= PART_OFF_BYTES + part8 + WT_BYTES) chs = 3;
    }
    const size_t part_bytes = (size_t)256 * (64 >> chs) * 2 * REC_FLOATS * 4;
    float* part = (float*)((char*)d_ws + PART_OFF_BYTES);
    unsigned short* WT = (unsigned short*)((char*)d_ws + PART_OFF_BYTES + part_bytes);

    prep_wt<<<dim3(16, 2, 3), 256, 0, stream>>>(Wq, Wk, Wv, WT);
    qkv_fused<<<dim3(256, 2), 512, 0, stream>>>(x, WT, qkv);

    const unsigned short* qb = qkv;
    const unsigned short* kb = qkv + K_OFF;
    const unsigned short* vtb = qkv + VT_OFF;
    diff_attn_pair<<<dim3(32, 4, 2 * (64 >> chs)), 256, 0, stream>>>(qb, kb, vtb, part, chs);
    diff_combine<<<dim3(64, 4), 256, 0, stream>>>(part, lq1, lq2, lk1, lk2, out, chs);
}

// Round 22
// 95.277 us; speedup vs baseline: 2.7339x; 1.6651x over previous
//
#include <hip/hip_runtime.h>
#include <hip/hip_bf16.h>

typedef __bf16 bf16x8 __attribute__((ext_vector_type(8)));
typedef float f32x4 __attribute__((ext_vector_type(4)));

#define LAMBDA_INIT 0.3555090675909693f
#define CEXP 0.18033688011112042f   // 0.125 * log2(e), folded into Q at projection

// ws layout (bytes):
//  q    : [0, 4.19M)       bf16 [16384][128] row-major, PRE-SCALED by CEXP
//  kimg : [4.19M, 8.39M)   bf16 [4][64][2][8 regions][64 slots][8]  (frag image)
//  vimg : [8.39M, 12.58M)  bf16 [4][64][16 regions][64 slots][8]    (frag image)
//  part : [12.58M, +68.2M) recs x 16640B (l[64] f32 + O[64][128] bf16), 8 slots/(b,t)
//  WT   : after part       bf16 W'[384][1024]
#define K_OFF   ((size_t)16384 * 128)
#define VT_OFF  ((size_t)2 * 16384 * 128)
#define PART_OFF_BYTES ((size_t)12582912)
#define REC_FLOATS 4160  // 64 l + 4096 words of bf16 O

__device__ __forceinline__ unsigned short f2bf(float f) {
    __hip_bfloat16 h = __float2bfloat16(f);
    unsigned short u;
    __builtin_memcpy(&u, &h, 2);
    return u;
}
__device__ __forceinline__ float bf2f(unsigned short u) {
    unsigned int x = ((unsigned int)u) << 16;
    float f;
    __builtin_memcpy(&f, &x, 4);
    return f;
}
__device__ __forceinline__ unsigned int cvt_pk_bf16(float a, float b) {
    unsigned int r;
    asm volatile("v_cvt_pk_bf16_f32 %0, %1, %2" : "=v"(r) : "v"(a), "v"(b));
    return r;
}

// ---------------- W pre-transpose: [1024][128] f32 -> [128][1024] bf16 ----------------
__global__ __launch_bounds__(256) void prep_wt(
    const float* __restrict__ Wq, const float* __restrict__ Wk,
    const float* __restrict__ Wv, unsigned short* __restrict__ WT) {
    const int kt = blockIdx.x, nt = blockIdx.y, mat = blockIdx.z;
    const float* W = (mat == 0) ? Wq : (mat == 1) ? Wk : Wv;
    unsigned short* O = WT + (size_t)mat * 128 * 1024;
    __shared__ float tb[64][65];
    const int r = threadIdx.x >> 2, c4 = (threadIdx.x & 3) * 16;
    for (int j = 0; j < 4; ++j) {
        float4 v = *(const float4*)&W[(size_t)(kt * 64 + r) * 128 + nt * 64 + c4 + j * 4];
        tb[r][c4 + j * 4 + 0] = v.x;
        tb[r][c4 + j * 4 + 1] = v.y;
        tb[r][c4 + j * 4 + 2] = v.z;
        tb[r][c4 + j * 4 + 3] = v.w;
    }
    __syncthreads();
    unsigned short tmp[16];
    for (int j = 0; j < 16; ++j) tmp[j] = f2bf(tb[c4 + j][r]);
    *(uint4*)&O[(size_t)(nt * 64 + r) * 1024 + kt * 64 + c4] = *(uint4*)&tmp[0];
    *(uint4*)&O[(size_t)(nt * 64 + r) * 1024 + kt * 64 + c4 + 8] = *(uint4*)&tmp[8];
}

// ---------------- Fused QKV GEMM, N-split: grid (256 row-tiles, 2 N-halves) ----------
__global__ __launch_bounds__(512) void qkv_fused(
    const float* __restrict__ x, const unsigned short* __restrict__ WT,
    unsigned short* __restrict__ qkv) {
    const int tid = threadIdx.x;
    const int l = tid & 63, w = tid >> 6;
    const int g = l >> 4, i16 = l & 15;
    const int rh = w >> 2, cp = w & 3;
    const int row0 = blockIdx.x * 64;
    const int np = blockIdx.y;
    const unsigned short* Wt = WT + (size_t)np * 192 * 1024;

    __shared__ unsigned short xs[64][72];
    __shared__ unsigned short wt[192][72];

    f32x4 acc[2][3];
    const f32x4 z4 = {0.f, 0.f, 0.f, 0.f};
    for (int rt = 0; rt < 2; ++rt)
        for (int ct = 0; ct < 3; ++ct) acc[rt][ct] = z4;

    const int xrow = tid >> 3, xcol = (tid & 7) * 8;
    const int wn = tid >> 3, wk8 = (tid & 7) * 8;
    const float* xp = &x[(size_t)(row0 + xrow) * 1024 + xcol];
    const unsigned short* wp = &Wt[(size_t)wn * 1024 + wk8];

    float4 ax0, ax1;
    uint4 aw0, aw1, aw2;

#define QI(k0_) do {                                                        \
        ax0 = *(const float4*)&xp[(k0_)];                                   \
        ax1 = *(const float4*)&xp[(k0_) + 4];                               \
        aw0 = *(const uint4*)&wp[(k0_)];                                    \
        aw1 = *(const uint4*)&wp[64 * 1024 + (k0_)];                        \
        aw2 = *(const uint4*)&wp[128 * 1024 + (k0_)];                       \
    } while (0)

#define QS() do {                                                           \
        *(ushort4*)&xs[xrow][xcol]     = make_ushort4(f2bf(ax0.x), f2bf(ax0.y), f2bf(ax0.z), f2bf(ax0.w)); \
        *(ushort4*)&xs[xrow][xcol + 4] = make_ushort4(f2bf(ax1.x), f2bf(ax1.y), f2bf(ax1.z), f2bf(ax1.w)); \
        *(uint4*)&wt[wn +   0][wk8] = aw0;                                  \
        *(uint4*)&wt[wn +  64][wk8] = aw1;                                  \
        *(uint4*)&wt[wn + 128][wk8] = aw2;                                  \
    } while (0)

    QI(0);
    #pragma unroll 1
    for (int k0 = 0; k0 < 1024; k0 += 64) {
        __syncthreads();
        QS();
        if (k0 + 64 < 1024) QI(k0 + 64);
        __syncthreads();
        bf16x8 af[2][2];
        #pragma unroll
        for (int rt = 0; rt < 2; ++rt)
            for (int cc = 0; cc < 2; ++cc)
                af[rt][cc] = *(const bf16x8*)&xs[rh * 32 + rt * 16 + i16][cc * 32 + 8 * g];
        #pragma unroll
        for (int ct = 0; ct < 3; ++ct)
            for (int cc = 0; cc < 2; ++cc) {
                bf16x8 bb = *(const bf16x8*)&wt[cp * 48 + ct * 16 + i16][cc * 32 + 8 * g];
                for (int rt = 0; rt < 2; ++rt)
                    acc[rt][ct] = __builtin_amdgcn_mfma_f32_16x16x32_bf16(af[rt][cc], bb, acc[rt][ct], 0, 0, 0);
            }
    }
#undef QI
#undef QS

    __syncthreads();
    unsigned short(*ts)[200] = (unsigned short(*)[200]) & wt[0][0];
    #pragma unroll
    for (int rt = 0; rt < 2; ++rt)
        for (int ct = 0; ct < 3; ++ct) {
            const float sc = (np == 0 && cp * 48 + ct * 16 < 128) ? CEXP : 1.0f;
            for (int r = 0; r < 4; ++r)
                ts[rh * 32 + rt * 16 + g * 4 + r][cp * 48 + ct * 16 + i16] = f2bf(acc[rt][ct][r] * sc);
        }
    __syncthreads();

    const int bq = row0 >> 12;
    const int s = (row0 >> 6) & 63;
    if (np == 0) {
        {
            unsigned short* outp = qkv + (size_t)row0 * 128;
            #pragma unroll
            for (int it = 0; it < 2; ++it) {
                int tr = it * 32 + (tid >> 4), dv0 = (tid & 15) * 8;
                *(uint4*)&outp[tr * 128 + dv0] = *(const uint4*)&ts[tr][dv0];
            }
        }
        {
            unsigned short* kimg = qkv + K_OFF + ((size_t)(bq * 64 + s) * 2) * 4096;
            int region = tid >> 6, slot = tid & 63;
            int row = (region >> 1) * 16 + (slot & 15);
            int d = 128 + (region & 1) * 32 + (slot >> 4) * 8;
            uint4 vv = *(const uint4*)&ts[row][d];
            *(uint4*)&kimg[(region * 64 + slot) * 8] = vv;
        }
    } else {
        {
            unsigned short* kimg = qkv + K_OFF + ((size_t)(bq * 64 + s) * 2 + 1) * 4096;
            int region = tid >> 6, slot = tid & 63;
            int row = (region >> 1) * 16 + (slot & 15);
            int d = (region & 1) * 32 + (slot >> 4) * 8;
            uint4 vv = *(const uint4*)&ts[row][d];
            *(uint4*)&kimg[(region * 64 + slot) * 8] = vv;
        }
        {
            unsigned short* vimg = qkv + VT_OFF + (size_t)(bq * 64 + s) * 8192;
            #pragma unroll
            for (int it = 0; it < 2; ++it) {
                int lin = it * 512 + tid;
                int region = lin >> 6, slot = lin & 63;
                int dv = 64 + (region >> 1) * 16 + (slot & 15);
                int kv0 = (region & 1) * 32 + (slot >> 4) * 8;
                unsigned short tmp[8];
                #pragma unroll
                for (int e = 0; e < 8; ++e) tmp[e] = ts[kv0 + e][dv];
                *(uint4*)&vimg[(region * 64 + slot) * 8] = *(uint4*)tmp;
            }
        }
    }
}

// ---------------- Differential causal flash attention, fixed-size chunks ----------------
// grid (32, 4, 2*nc): z = c*2+branch, nc = 64>>chs chunks of EXACTLY (1<<chs)
// kv-tiles. Block c of pair (t_e=62-2bxe, t_o=63-2bxe) covers
// [c<<chs, min(n,(c+1)<<chs)); dead chunks exit instantly. COMPLEMENT SWIZZLE
// bxe=(c&1)?31-bx:bx -> each CU gets 4-5 equal-duration live blocks.
// __launch_bounds__(256,3): empirical VGPR cap ~ 256/w on this toolchain
// (w=3 -> 84 = natural, NO spill; w=4 -> 64 spill 239MB; w=5 -> 48 spill 519MB).
// At 84 VGPR hardware still admits 5-6 waves/SIMD, LDS 32KB admits 5 blocks.
// Body: fused QK, ksf dbuf, 2 barriers/tile, V in regs.
__global__ __launch_bounds__(256, 3) void diff_attn_pair(
    const unsigned short* __restrict__ q, const unsigned short* __restrict__ kimg,
    const unsigned short* __restrict__ vimg,
    float* __restrict__ part, int chs) {
    const int bx = blockIdx.x, b = blockIdx.y;
    const int c = blockIdx.z >> 1, branch = blockIdx.z & 1;
    const int bxe = (c & 1) ? (31 - bx) : bx;
    const int t_o = 63 - 2 * bxe, t_e = t_o - 1;
    const int n = t_o + 1;
    const int s_lo = c << chs;
    if (s_lo >= n) return;  // dead chunk
    const int smax = min(n, s_lo + (1 << chs));

    const int tid = threadIdx.x;
    const int l = tid & 63, w = tid >> 6;
    const int gq = l >> 4, i16 = l & 15;
    const float NEGINF = -__builtin_inff();

    __shared__ unsigned short ksf[2][4096];  // 16 KB K frag image, dbuf
    __shared__ unsigned short psf[8192];     // 16 KB P (both qsets)

    const int rshift = 6 - chs;  // record slots per (b,t)
    float* recA = part + ((((size_t)(b * 64 + t_e) << rshift) + c) * 2 + branch) * REC_FLOATS;
    float* recB = part + ((((size_t)(b * 64 + t_o) << rshift) + c) * 2 + branch) * REC_FLOATS;
    const bool emptyA = (s_lo > t_e);

    const size_t bbase = (size_t)b * 4096;
    const unsigned short* kimg_b = kimg + (size_t)b * 524288;
    const unsigned short* vimg_b = vimg + (size_t)b * 524288;
    const int tid8 = tid * 8;
    const int l8 = l * 8;
    const f32x4 z4 = {0.f, 0.f, 0.f, 0.f};

    bf16x8 qfA[2], qfB[2];
    #pragma unroll
    for (int cc = 0; cc < 2; ++cc) {
        qfA[cc] = *(const bf16x8*)&q[(bbase + t_e * 64 + w * 16 + i16) * 128 + branch * 64 + cc * 32 + 8 * gq];
        qfB[cc] = *(const bf16x8*)&q[(bbase + t_o * 64 + w * 16 + i16) * 128 + branch * 64 + cc * 32 + 8 * gq];
    }

    float lsumA = 0.f, lsumB = 0.f;
    f32x4 acc[2][4][2];
    for (int qs = 0; qs < 2; ++qs)
        for (int qg = 0; qg < 4; ++qg)
            for (int j = 0; j < 2; ++j) acc[qs][qg][j] = z4;

    int pdst[4];
    #pragma unroll
    for (int cb = 0; cb < 4; ++cb)
        pdst[cb] = ((w * 2 + (cb >> 1)) * 64 + ((cb & 1) * 2 + (gq >> 1)) * 16 + i16) * 8 + (gq & 1) * 4;

    uint4 kr0, kr1;
    bf16x8 vb00, vb01, vb10, vb11;

#define K_ISSUE(s_) do {                                                            \
        const unsigned short* kp = &kimg_b[((size_t)(s_) * 2 + branch) * 4096];     \
        kr0 = *(const uint4*)&kp[tid8];                                             \
        kr1 = *(const uint4*)&kp[tid8 + 2048];                                      \
    } while (0)
#define V_ISSUE(s_) do {                                                            \
        const unsigned short* vp = &vimg_b[(size_t)(s_) * 8192 + w * 2048];         \
        vb00 = *(const bf16x8*)&vp[l8];                                             \
        vb01 = *(const bf16x8*)&vp[512 + l8];                                       \
        vb10 = *(const bf16x8*)&vp[1024 + l8];                                      \
        vb11 = *(const bf16x8*)&vp[1536 + l8];                                      \
    } while (0)

    K_ISSUE(s_lo);
    V_ISSUE(s_lo);
    int pb = 0;
    #pragma unroll 1
    for (int s = s_lo; s < smax; ++s) {
        *(uint4*)&ksf[pb][tid8] = kr0;
        *(uint4*)&ksf[pb][tid8 + 2048] = kr1;
        if (s + 1 < smax) K_ISSUE(s + 1);
        __syncthreads();   // merged: ksf[pb] ready + prev PV done reading psf
        const bool aAct = (s != t_o);

        f32x4 scA[4], scB[4];
        for (int cb = 0; cb < 4; ++cb) { scA[cb] = z4; scB[cb] = z4; }
        __builtin_amdgcn_s_setprio(1);
        #pragma unroll
        for (int cb = 0; cb < 4; ++cb)
            for (int cc = 0; cc < 2; ++cc) {
                bf16x8 kf = *(const bf16x8*)&ksf[pb][((cb * 2 + cc) * 64 + l) * 8];
                scA[cb] = __builtin_amdgcn_mfma_f32_16x16x32_bf16(kf, qfA[cc], scA[cb], 0, 0, 0);
                scB[cb] = __builtin_amdgcn_mfma_f32_16x16x32_bf16(kf, qfB[cc], scB[cb], 0, 0, 0);
            }
        __builtin_amdgcn_s_setprio(0);

        if (aAct) {
            if (s == t_e) {
                int ql = w * 16 + i16;
                for (int cb = 0; cb < 4; ++cb)
                    for (int r = 0; r < 4; ++r)
                        if (cb * 16 + gq * 4 + r > ql) scA[cb][r] = NEGINF;
            }
            #pragma unroll
            for (int cb = 0; cb < 4; ++cb) {
                float p0 = exp2f(scA[cb][0]);
                float p1 = exp2f(scA[cb][1]);
                float p2 = exp2f(scA[cb][2]);
                float p3 = exp2f(scA[cb][3]);
                lsumA += (p0 + p1) + (p2 + p3);
                uint2 pw;
                pw.x = cvt_pk_bf16(p0, p1);
                pw.y = cvt_pk_bf16(p2, p3);
                *(uint2*)&psf[pdst[cb]] = pw;
            }
        }
        {
            if (s == t_o) {
                int ql = w * 16 + i16;
                for (int cb = 0; cb < 4; ++cb)
                    for (int r = 0; r < 4; ++r)
                        if (cb * 16 + gq * 4 + r > ql) scB[cb][r] = NEGINF;
            }
            #pragma unroll
            for (int cb = 0; cb < 4; ++cb) {
                float p0 = exp2f(scB[cb][0]);
                float p1 = exp2f(scB[cb][1]);
                float p2 = exp2f(scB[cb][2]);
                float p3 = exp2f(scB[cb][3]);
                lsumB += (p0 + p1) + (p2 + p3);
                uint2 pw;
                pw.x = cvt_pk_bf16(p0, p1);
                pw.y = cvt_pk_bf16(p2, p3);
                *(uint2*)&psf[4096 + pdst[cb]] = pw;
            }
        }
        __syncthreads();   // psf complete

        __builtin_amdgcn_s_setprio(1);
        if (aAct) {
            #pragma unroll
            for (int qg = 0; qg < 4; ++qg) {
                bf16x8 pa0 = *(const bf16x8*)&psf[(qg * 2 + 0) * 512 + l8];
                bf16x8 pa1 = *(const bf16x8*)&psf[(qg * 2 + 1) * 512 + l8];
                acc[0][qg][0] = __builtin_amdgcn_mfma_f32_16x16x32_bf16(pa0, vb00, acc[0][qg][0], 0, 0, 0);
                acc[0][qg][0] = __builtin_amdgcn_mfma_f32_16x16x32_bf16(pa1, vb01, acc[0][qg][0], 0, 0, 0);
                acc[0][qg][1] = __builtin_amdgcn_mfma_f32_16x16x32_bf16(pa0, vb10, acc[0][qg][1], 0, 0, 0);
                acc[0][qg][1] = __builtin_amdgcn_mfma_f32_16x16x32_bf16(pa1, vb11, acc[0][qg][1], 0, 0, 0);
            }
        }
        #pragma unroll
        for (int qg = 0; qg < 4; ++qg) {
            bf16x8 pa0 = *(const bf16x8*)&psf[4096 + (qg * 2 + 0) * 512 + l8];
            bf16x8 pa1 = *(const bf16x8*)&psf[4096 + (qg * 2 + 1) * 512 + l8];
            acc[1][qg][0] = __builtin_amdgcn_mfma_f32_16x16x32_bf16(pa0, vb00, acc[1][qg][0], 0, 0, 0);
            acc[1][qg][0] = __builtin_amdgcn_mfma_f32_16x16x32_bf16(pa1, vb01, acc[1][qg][0], 0, 0, 0);
            acc[1][qg][1] = __builtin_amdgcn_mfma_f32_16x16x32_bf16(pa0, vb10, acc[1][qg][1], 0, 0, 0);
            acc[1][qg][1] = __builtin_amdgcn_mfma_f32_16x16x32_bf16(pa1, vb11, acc[1][qg][1], 0, 0, 0);
        }
        __builtin_amdgcn_s_setprio(0);
        if (s + 1 < smax) V_ISSUE(s + 1);
        pb ^= 1;
    }
#undef K_ISSUE
#undef V_ISSUE

    lsumA += __shfl_xor(lsumA, 16);
    lsumA += __shfl_xor(lsumA, 32);
    lsumB += __shfl_xor(lsumB, 16);
    lsumB += __shfl_xor(lsumB, 32);
    if (!emptyA) {
        if (gq == 0) recA[w * 16 + i16] = lsumA;
        unsigned short* OA = (unsigned short*)(recA + 64);
        for (int qg = 0; qg < 4; ++qg)
            for (int j = 0; j < 2; ++j)
                for (int r = 0; r < 4; ++r)
                    OA[(qg * 16 + gq * 4 + r) * 128 + (w * 2 + j) * 16 + i16] = f2bf(acc[0][qg][j][r]);
    }
    {
        if (gq == 0) recB[w * 16 + i16] = lsumB;
        unsigned short* OB = (unsigned short*)(recB + 64);
        for (int qg = 0; qg < 4; ++qg)
            for (int j = 0; j < 2; ++j)
                for (int r = 0; r < 4; ++r)
                    OB[(qg * 16 + gq * 4 + r) * 128 + (w * 2 + j) * 16 + i16] = f2bf(acc[1][qg][j][r]);
    }
}

// ---------------- combine: sum valid chunks per branch, normalize, o1 - lam*o2 ----------
__global__ __launch_bounds__(256) void diff_combine(
    const float* __restrict__ part,
    const float* __restrict__ lq1, const float* __restrict__ lq2,
    const float* __restrict__ lk1, const float* __restrict__ lk2,
    float* __restrict__ out, int chs) {
    const int t = blockIdx.x, b = blockIdx.y;
    const int tid = threadIdx.x;
    const int nc = 64 >> chs;
    const int rshift = 6 - chs;
    __shared__ float sl[2][64];
    __shared__ float s_lam;

    const float* recbase = part + ((size_t)(b * 64 + t) << rshift) * 2 * REC_FLOATS;

    if (tid < 64) {
        float s1 = lq1[tid] * lk1[tid];
        float s2 = lq2[tid] * lk2[tid];
        for (int off = 32; off > 0; off >>= 1) {
            s1 += __shfl_xor(s1, off);
            s2 += __shfl_xor(s2, off);
        }
        if (tid == 0) s_lam = expf(s1) - expf(s2) + LAMBDA_INIT;
    }
    if (tid < 128) {
        int r = tid & 63, br = tid >> 6;
        float acc = 0.f;
        for (int c = 0; c < nc; ++c) {
            if ((c << chs) > t) break;
            acc += recbase[(c * 2 + br) * REC_FLOATS + r];
        }
        sl[br][r] = acc;
    }
    __syncthreads();
    const float lam = s_lam;

    float* op = out + ((size_t)b * 4096 + (size_t)t * 64) * 128;
    for (int grp = 0; grp < 4; ++grp) {
        int gid = grp * 256 + tid;
        int e = gid * 8;
        int row = e >> 7;
        float o1[8] = {0, 0, 0, 0, 0, 0, 0, 0}, o2[8] = {0, 0, 0, 0, 0, 0, 0, 0};
        for (int c = 0; c < nc; ++c) {
            if ((c << chs) > t) break;
            const unsigned short* O0 = (const unsigned short*)(recbase + (c * 2 + 0) * REC_FLOATS + 64);
            const unsigned short* O1 = (const unsigned short*)(recbase + (c * 2 + 1) * REC_FLOATS + 64);
            uint4 u0 = *(const uint4*)&O0[e];
            uint4 u1 = *(const uint4*)&O1[e];
            const unsigned short* e0 = (const unsigned short*)&u0;
            const unsigned short* e1 = (const unsigned short*)&u1;
            #pragma unroll
            for (int j = 0; j < 8; ++j) {
                o1[j] += bf2f(e0[j]);
                o2[j] += bf2f(e1[j]);
            }
        }
        float l1inv = 1.0f / sl[0][row], l2inv = 1.0f / sl[1][row];
        float res[8];
        #pragma unroll
        for (int j = 0; j < 8; ++j) res[j] = o1[j] * l1inv - lam * o2[j] * l2inv;
        *(float4*)&op[e] = *(float4*)&res[0];
        *(float4*)&op[e + 4] = *(float4*)&res[4];
    }
}

extern "C" void kernel_launch(void* const* d_in, const int* in_sizes, int n_in,
                              void* d_out, int out_size, void* d_ws, size_t ws_size,
                              hipStream_t stream) {
    const float* x   = (const float*)d_in[0];
    const float* Wq  = (const float*)d_in[1];
    const float* Wk  = (const float*)d_in[2];
    const float* Wv  = (const float*)d_in[3];
    const float* lq1 = (const float*)d_in[4];
    const float* lq2 = (const float*)d_in[5];
    const float* lk1 = (const float*)d_in[6];
    const float* lk2 = (const float*)d_in[7];
    float* out = (float*)d_out;
    unsigned short* qkv = (unsigned short*)d_ws;

    // chunk size 8 tiles (chs=3, 8 record slots) if ws fits; else 16 (chs=4)
    const size_t WT_BYTES = (size_t)384 * 1024 * 2;
    int chs = 4;
    {
        size_t part8 = (size_t)256 * 8 * 2 * REC_FLOATS * 4;
        if (ws_size >= PART_OFF_BYTES + part8 + WT_BYTES) chs = 3;
    }
    const size_t part_bytes = (size_t)256 * (64 >> chs) * 2 * REC_FLOATS * 4;
    float* part = (float*)((char*)d_ws + PART_OFF_BYTES);
    unsigned short* WT = (unsigned short*)((char*)d_ws + PART_OFF_BYTES + part_bytes);

    prep_wt<<<dim3(16, 2, 3), 256, 0, stream>>>(Wq, Wk, Wv, WT);
    qkv_fused<<<dim3(256, 2), 512, 0, stream>>>(x, WT, qkv);

    const unsigned short* qb = qkv;
    const unsigned short* kb = qkv + K_OFF;
    const unsigned short* vtb = qkv + VT_OFF;
    diff_attn_pair<<<dim3(32, 4, 2 * (64 >> chs)), 256, 0, stream>>>(qb, kb, vtb, part, chs);
    diff_combine<<<dim3(64, 4), 256, 0, stream>>>(part, lq1, lq2, lk1, lk2, out, chs);
}

// Round 23
// 89.959 us; speedup vs baseline: 2.8956x; 1.0591x over previous
//
#include <hip/hip_runtime.h>
#include <hip/hip_bf16.h>

typedef __bf16 bf16x8 __attribute__((ext_vector_type(8)));
typedef float f32x4 __attribute__((ext_vector_type(4)));

#define LAMBDA_INIT 0.3555090675909693f
#define CEXP 0.18033688011112042f   // 0.125 * log2(e), folded into Q at projection

// ws layout (bytes):
//  q    : [0, 4.19M)       bf16 [16384][128] row-major, PRE-SCALED by CEXP
//  kimg : [4.19M, 8.39M)   bf16 [4][64][2][8 regions][64 slots][8]  (frag image)
//  vimg : [8.39M, 12.58M)  bf16 [4][64][16 regions][64 slots][8]    (frag image)
//  part : [12.58M, +34.1M) recs x 16640B (l[64] f32 + O[64][128] bf16)
//  WT   : after part       bf16 W'[384][1024]
#define K_OFF   ((size_t)16384 * 128)
#define VT_OFF  ((size_t)2 * 16384 * 128)
#define PART_OFF_BYTES ((size_t)12582912)
#define REC_FLOATS 4160  // 64 l + 4096 words of bf16 O

__device__ __forceinline__ unsigned short f2bf(float f) {
    __hip_bfloat16 h = __float2bfloat16(f);
    unsigned short u;
    __builtin_memcpy(&u, &h, 2);
    return u;
}
__device__ __forceinline__ float bf2f(unsigned short u) {
    unsigned int x = ((unsigned int)u) << 16;
    float f;
    __builtin_memcpy(&f, &x, 4);
    return f;
}
__device__ __forceinline__ unsigned int cvt_pk_bf16(float a, float b) {
    unsigned int r;
    asm volatile("v_cvt_pk_bf16_f32 %0, %1, %2" : "=v"(r) : "v"(a), "v"(b));
    return r;
}

// ---------------- W pre-transpose: [1024][128] f32 -> [128][1024] bf16 ----------------
__global__ __launch_bounds__(256) void prep_wt(
    const float* __restrict__ Wq, const float* __restrict__ Wk,
    const float* __restrict__ Wv, unsigned short* __restrict__ WT) {
    const int kt = blockIdx.x, nt = blockIdx.y, mat = blockIdx.z;
    const float* W = (mat == 0) ? Wq : (mat == 1) ? Wk : Wv;
    unsigned short* O = WT + (size_t)mat * 128 * 1024;
    __shared__ float tb[64][65];
    const int r = threadIdx.x >> 2, c4 = (threadIdx.x & 3) * 16;
    for (int j = 0; j < 4; ++j) {
        float4 v = *(const float4*)&W[(size_t)(kt * 64 + r) * 128 + nt * 64 + c4 + j * 4];
        tb[r][c4 + j * 4 + 0] = v.x;
        tb[r][c4 + j * 4 + 1] = v.y;
        tb[r][c4 + j * 4 + 2] = v.z;
        tb[r][c4 + j * 4 + 3] = v.w;
    }
    __syncthreads();
    unsigned short tmp[16];
    for (int j = 0; j < 16; ++j) tmp[j] = f2bf(tb[c4 + j][r]);
    *(uint4*)&O[(size_t)(nt * 64 + r) * 1024 + kt * 64 + c4] = *(uint4*)&tmp[0];
    *(uint4*)&O[(size_t)(nt * 64 + r) * 1024 + kt * 64 + c4 + 8] = *(uint4*)&tmp[8];
}

// ---------------- Fused QKV GEMM, N-split: grid (256 row-tiles, 2 N-halves) ----------
// Linear ids i and i+256 land on the SAME CU -> the two N-halves of a row-tile
// share the x tile via L2 (x read once from HBM). 2 blocks x 512 thr = 16
// waves/CU. np=0 -> q (CEXP-scaled) + K-branch0 image; np=1 -> K-branch1 + V image.
__global__ __launch_bounds__(512) void qkv_fused(
    const float* __restrict__ x, const unsigned short* __restrict__ WT,
    unsigned short* __restrict__ qkv) {
    const int tid = threadIdx.x;
    const int l = tid & 63, w = tid >> 6;
    const int g = l >> 4, i16 = l & 15;
    const int rh = w >> 2, cp = w & 3;
    const int row0 = blockIdx.x * 64;
    const int np = blockIdx.y;
    const unsigned short* Wt = WT + (size_t)np * 192 * 1024;

    __shared__ unsigned short xs[64][72];
    __shared__ unsigned short wt[192][72];

    f32x4 acc[2][3];
    const f32x4 z4 = {0.f, 0.f, 0.f, 0.f};
    for (int rt = 0; rt < 2; ++rt)
        for (int ct = 0; ct < 3; ++ct) acc[rt][ct] = z4;

    const int xrow = tid >> 3, xcol = (tid & 7) * 8;
    const int wn = tid >> 3, wk8 = (tid & 7) * 8;
    const float* xp = &x[(size_t)(row0 + xrow) * 1024 + xcol];
    const unsigned short* wp = &Wt[(size_t)wn * 1024 + wk8];

    float4 ax0, ax1;
    uint4 aw0, aw1, aw2;

#define QI(k0_) do {                                                        \
        ax0 = *(const float4*)&xp[(k0_)];                                   \
        ax1 = *(const float4*)&xp[(k0_) + 4];                               \
        aw0 = *(const uint4*)&wp[(k0_)];                                    \
        aw1 = *(const uint4*)&wp[64 * 1024 + (k0_)];                        \
        aw2 = *(const uint4*)&wp[128 * 1024 + (k0_)];                       \
    } while (0)

#define QS() do {                                                           \
        *(ushort4*)&xs[xrow][xcol]     = make_ushort4(f2bf(ax0.x), f2bf(ax0.y), f2bf(ax0.z), f2bf(ax0.w)); \
        *(ushort4*)&xs[xrow][xcol + 4] = make_ushort4(f2bf(ax1.x), f2bf(ax1.y), f2bf(ax1.z), f2bf(ax1.w)); \
        *(uint4*)&wt[wn +   0][wk8] = aw0;                                  \
        *(uint4*)&wt[wn +  64][wk8] = aw1;                                  \
        *(uint4*)&wt[wn + 128][wk8] = aw2;                                  \
    } while (0)

    QI(0);
    #pragma unroll 1
    for (int k0 = 0; k0 < 1024; k0 += 64) {
        __syncthreads();
        QS();
        if (k0 + 64 < 1024) QI(k0 + 64);
        __syncthreads();
        bf16x8 af[2][2];
        #pragma unroll
        for (int rt = 0; rt < 2; ++rt)
            for (int cc = 0; cc < 2; ++cc)
                af[rt][cc] = *(const bf16x8*)&xs[rh * 32 + rt * 16 + i16][cc * 32 + 8 * g];
        #pragma unroll
        for (int ct = 0; ct < 3; ++ct)
            for (int cc = 0; cc < 2; ++cc) {
                bf16x8 bb = *(const bf16x8*)&wt[cp * 48 + ct * 16 + i16][cc * 32 + 8 * g];
                for (int rt = 0; rt < 2; ++rt)
                    acc[rt][ct] = __builtin_amdgcn_mfma_f32_16x16x32_bf16(af[rt][cc], bb, acc[rt][ct], 0, 0, 0);
            }
    }
#undef QI
#undef QS

    __syncthreads();
    unsigned short(*ts)[200] = (unsigned short(*)[200]) & wt[0][0];
    #pragma unroll
    for (int rt = 0; rt < 2; ++rt)
        for (int ct = 0; ct < 3; ++ct) {
            const float sc = (np == 0 && cp * 48 + ct * 16 < 128) ? CEXP : 1.0f;
            for (int r = 0; r < 4; ++r)
                ts[rh * 32 + rt * 16 + g * 4 + r][cp * 48 + ct * 16 + i16] = f2bf(acc[rt][ct][r] * sc);
        }
    __syncthreads();

    const int bq = row0 >> 12;
    const int s = (row0 >> 6) & 63;
    if (np == 0) {
        {
            unsigned short* outp = qkv + (size_t)row0 * 128;
            #pragma unroll
            for (int it = 0; it < 2; ++it) {
                int tr = it * 32 + (tid >> 4), dv0 = (tid & 15) * 8;
                *(uint4*)&outp[tr * 128 + dv0] = *(const uint4*)&ts[tr][dv0];
            }
        }
        {
            unsigned short* kimg = qkv + K_OFF + ((size_t)(bq * 64 + s) * 2) * 4096;
            int region = tid >> 6, slot = tid & 63;
            int row = (region >> 1) * 16 + (slot & 15);
            int d = 128 + (region & 1) * 32 + (slot >> 4) * 8;
            uint4 vv = *(const uint4*)&ts[row][d];
            *(uint4*)&kimg[(region * 64 + slot) * 8] = vv;
        }
    } else {
        {
            unsigned short* kimg = qkv + K_OFF + ((size_t)(bq * 64 + s) * 2 + 1) * 4096;
            int region = tid >> 6, slot = tid & 63;
            int row = (region >> 1) * 16 + (slot & 15);
            int d = (region & 1) * 32 + (slot >> 4) * 8;
            uint4 vv = *(const uint4*)&ts[row][d];
            *(uint4*)&kimg[(region * 64 + slot) * 8] = vv;
        }
        {
            unsigned short* vimg = qkv + VT_OFF + (size_t)(bq * 64 + s) * 8192;
            #pragma unroll
            for (int it = 0; it < 2; ++it) {
                int lin = it * 512 + tid;
                int region = lin >> 6, slot = lin & 63;
                int dv = 64 + (region >> 1) * 16 + (slot & 15);
                int kv0 = (region & 1) * 32 + (slot >> 4) * 8;
                unsigned short tmp[8];
                #pragma unroll
                for (int e = 0; e < 8; ++e) tmp[e] = ts[kv0 + e][dv];
                *(uint4*)&vimg[(region * 64 + slot) * 8] = *(uint4*)tmp;
            }
        }
    }
}

// ---------------- Differential causal flash attention, single-barrier pipeline ------
// grid (32, 4, 8): z = c*2+branch, nc=4 chunks. Paired rows (t_e, t_o),
// COMPLEMENT SWIZZLE bxe = (c&1)?31-bx:bx (same-CU blocks complementary).
// ONE barrier per tile: [store ksf[s&1]; issue K(s+1)] -> barrier ->
// MFMA cluster {PV(s-1) || QK(s)} -> issue V(s) -> SM(s) -> psf[s&1].
// LDS 48KB (ksf 2x8K + psf 2x16K), 3 blocks/CU, 84 VGPR no spill.
__global__ __launch_bounds__(256, 3) void diff_attn_pair(
    const unsigned short* __restrict__ q, const unsigned short* __restrict__ kimg,
    const unsigned short* __restrict__ vimg,
    float* __restrict__ part, int ncs) {
    const int bx = blockIdx.x, b = blockIdx.y;
    const int c = blockIdx.z >> 1, branch = blockIdx.z & 1;
    const int bxe = (c & 1) ? (31 - bx) : bx;
    const int t_o = 63 - 2 * bxe, t_e = t_o - 1;
    const int n = t_o + 1;
    const int s_lo = (c * n) >> ncs, smax = ((c + 1) * n) >> ncs;

    if (s_lo >= smax) return;

    const int tid = threadIdx.x;
    const int l = tid & 63, w = tid >> 6;
    const int gq = l >> 4, i16 = l & 15;
    const float NEGINF = -__builtin_inff();

    __shared__ unsigned short ksf[2][4096];
    __shared__ unsigned short psf[2][8192];

    float* recA = part + ((((size_t)(b * 64 + t_e) << ncs) + c) * 2 + branch) * REC_FLOATS;
    float* recB = part + ((((size_t)(b * 64 + t_o) << ncs) + c) * 2 + branch) * REC_FLOATS;
    const bool emptyA = (s_lo > t_e);

    const size_t bbase = (size_t)b * 4096;
    const unsigned short* kimg_b = kimg + (size_t)b * 524288;
    const unsigned short* vimg_b = vimg + (size_t)b * 524288;
    const int tid8 = tid * 8;
    const int l8 = l * 8;
    const f32x4 z4 = {0.f, 0.f, 0.f, 0.f};

    bf16x8 qfA[2], qfB[2];
    #pragma unroll
    for (int cc = 0; cc < 2; ++cc) {
        qfA[cc] = *(const bf16x8*)&q[(bbase + t_e * 64 + w * 16 + i16) * 128 + branch * 64 + cc * 32 + 8 * gq];
        qfB[cc] = *(const bf16x8*)&q[(bbase + t_o * 64 + w * 16 + i16) * 128 + branch * 64 + cc * 32 + 8 * gq];
    }

    float lsumA = 0.f, lsumB = 0.f;
    f32x4 acc[2][4][2];
    for (int qs = 0; qs < 2; ++qs)
        for (int qg = 0; qg < 4; ++qg)
            for (int j = 0; j < 2; ++j) acc[qs][qg][j] = z4;

    int pdst[4];
    #pragma unroll
    for (int cb = 0; cb < 4; ++cb)
        pdst[cb] = ((w * 2 + (cb >> 1)) * 64 + ((cb & 1) * 2 + (gq >> 1)) * 16 + i16) * 8 + (gq & 1) * 4;

    uint4 kr0, kr1;
    bf16x8 vb00, vb01, vb10, vb11;

#define K_ISSUE(s_) do {                                                            \
        const unsigned short* kp = &kimg_b[((size_t)(s_) * 2 + branch) * 4096];     \
        kr0 = *(const uint4*)&kp[tid8];                                             \
        kr1 = *(const uint4*)&kp[tid8 + 2048];                                      \
    } while (0)
#define V_ISSUE(s_) do {                                                            \
        const unsigned short* vp = &vimg_b[(size_t)(s_) * 8192 + w * 2048];         \
        vb00 = *(const bf16x8*)&vp[l8];                                             \
        vb01 = *(const bf16x8*)&vp[512 + l8];                                       \
        vb10 = *(const bf16x8*)&vp[1024 + l8];                                      \
        vb11 = *(const bf16x8*)&vp[1536 + l8];                                      \
    } while (0)

#define PV_CLUSTER(pp_, aPrev_) do {                                                \
        if (aPrev_) {                                                               \
            _Pragma("unroll")                                                       \
            for (int qg = 0; qg < 4; ++qg) {                                        \
                bf16x8 pa0 = *(const bf16x8*)&psf[pp_][(qg * 2 + 0) * 512 + l8];    \
                bf16x8 pa1 = *(const bf16x8*)&psf[pp_][(qg * 2 + 1) * 512 + l8];    \
                acc[0][qg][0] = __builtin_amdgcn_mfma_f32_16x16x32_bf16(pa0, vb00, acc[0][qg][0], 0, 0, 0); \
                acc[0][qg][0] = __builtin_amdgcn_mfma_f32_16x16x32_bf16(pa1, vb01, acc[0][qg][0], 0, 0, 0); \
                acc[0][qg][1] = __builtin_amdgcn_mfma_f32_16x16x32_bf16(pa0, vb10, acc[0][qg][1], 0, 0, 0); \
                acc[0][qg][1] = __builtin_amdgcn_mfma_f32_16x16x32_bf16(pa1, vb11, acc[0][qg][1], 0, 0, 0); \
            }                                                                       \
        }                                                                           \
        _Pragma("unroll")                                                           \
        for (int qg = 0; qg < 4; ++qg) {                                            \
            bf16x8 pa0 = *(const bf16x8*)&psf[pp_][4096 + (qg * 2 + 0) * 512 + l8]; \
            bf16x8 pa1 = *(const bf16x8*)&psf[pp_][4096 + (qg * 2 + 1) * 512 + l8]; \
            acc[1][qg][0] = __builtin_amdgcn_mfma_f32_16x16x32_bf16(pa0, vb00, acc[1][qg][0], 0, 0, 0); \
            acc[1][qg][0] = __builtin_amdgcn_mfma_f32_16x16x32_bf16(pa1, vb01, acc[1][qg][0], 0, 0, 0); \
            acc[1][qg][1] = __builtin_amdgcn_mfma_f32_16x16x32_bf16(pa0, vb10, acc[1][qg][1], 0, 0, 0); \
            acc[1][qg][1] = __builtin_amdgcn_mfma_f32_16x16x32_bf16(pa1, vb11, acc[1][qg][1], 0, 0, 0); \
        }                                                                           \
    } while (0)

    K_ISSUE(s_lo);
    #pragma unroll 1
    for (int s = s_lo; s < smax; ++s) {
        const int kb = s & 1;
        *(uint4*)&ksf[kb][tid8] = kr0;
        *(uint4*)&ksf[kb][tid8 + 2048] = kr1;
        if (s + 1 < smax) K_ISSUE(s + 1);
        __syncthreads();   // the ONE barrier

        __builtin_amdgcn_s_setprio(1);
        if (s > s_lo) PV_CLUSTER((s - 1) & 1, (s - 1) != t_o);
        f32x4 scA[4], scB[4];
        for (int cb = 0; cb < 4; ++cb) { scA[cb] = z4; scB[cb] = z4; }
        #pragma unroll
        for (int cb = 0; cb < 4; ++cb)
            for (int cc = 0; cc < 2; ++cc) {
                bf16x8 kf = *(const bf16x8*)&ksf[kb][((cb * 2 + cc) * 64 + l) * 8];
                scA[cb] = __builtin_amdgcn_mfma_f32_16x16x32_bf16(kf, qfA[cc], scA[cb], 0, 0, 0);
                scB[cb] = __builtin_amdgcn_mfma_f32_16x16x32_bf16(kf, qfB[cc], scB[cb], 0, 0, 0);
            }
        __builtin_amdgcn_s_setprio(0);
        V_ISSUE(s);

        const bool aAct = (s != t_o);
        if (aAct) {
            if (s == t_e) {
                int ql = w * 16 + i16;
                for (int cb = 0; cb < 4; ++cb)
                    for (int r = 0; r < 4; ++r)
                        if (cb * 16 + gq * 4 + r > ql) scA[cb][r] = NEGINF;
            }
            #pragma unroll
            for (int cb = 0; cb < 4; ++cb) {
                float p0 = exp2f(scA[cb][0]);
                float p1 = exp2f(scA[cb][1]);
                float p2 = exp2f(scA[cb][2]);
                float p3 = exp2f(scA[cb][3]);
                lsumA += (p0 + p1) + (p2 + p3);
                uint2 pw;
                pw.x = cvt_pk_bf16(p0, p1);
                pw.y = cvt_pk_bf16(p2, p3);
                *(uint2*)&psf[kb][pdst[cb]] = pw;
            }
        }
        {
            if (s == t_o) {
                int ql = w * 16 + i16;
                for (int cb = 0; cb < 4; ++cb)
                    for (int r = 0; r < 4; ++r)
                        if (cb * 16 + gq * 4 + r > ql) scB[cb][r] = NEGINF;
            }
            #pragma unroll
            for (int cb = 0; cb < 4; ++cb) {
                float p0 = exp2f(scB[cb][0]);
                float p1 = exp2f(scB[cb][1]);
                float p2 = exp2f(scB[cb][2]);
                float p3 = exp2f(scB[cb][3]);
                lsumB += (p0 + p1) + (p2 + p3);
                uint2 pw;
                pw.x = cvt_pk_bf16(p0, p1);
                pw.y = cvt_pk_bf16(p2, p3);
                *(uint2*)&psf[kb][4096 + pdst[cb]] = pw;
            }
        }
    }

    // drain
    __syncthreads();
    __builtin_amdgcn_s_setprio(1);
    PV_CLUSTER((smax - 1) & 1, (smax - 1) != t_o);
    __builtin_amdgcn_s_setprio(0);
#undef K_ISSUE
#undef V_ISSUE
#undef PV_CLUSTER

    lsumA += __shfl_xor(lsumA, 16);
    lsumA += __shfl_xor(lsumA, 32);
    lsumB += __shfl_xor(lsumB, 16);
    lsumB += __shfl_xor(lsumB, 32);
    if (!emptyA) {
        if (gq == 0) recA[w * 16 + i16] = lsumA;
        unsigned short* OA = (unsigned short*)(recA + 64);
        for (int qg = 0; qg < 4; ++qg)
            for (int j = 0; j < 2; ++j)
                for (int r = 0; r < 4; ++r)
                    OA[(qg * 16 + gq * 4 + r) * 128 + (w * 2 + j) * 16 + i16] = f2bf(acc[0][qg][j][r]);
    }
    {
        if (gq == 0) recB[w * 16 + i16] = lsumB;
        unsigned short* OB = (unsigned short*)(recB + 64);
        for (int qg = 0; qg < 4; ++qg)
            for (int j = 0; j < 2; ++j)
                for (int r = 0; r < 4; ++r)
                    OB[(qg * 16 + gq * 4 + r) * 128 + (w * 2 + j) * 16 + i16] = f2bf(acc[1][qg][j][r]);
    }
}

// ---------------- combine: grid (64,4,2); z halves the output elements ----------------
__global__ __launch_bounds__(256) void diff_combine(
    const float* __restrict__ part,
    const float* __restrict__ lq1, const float* __restrict__ lq2,
    const float* __restrict__ lk1, const float* __restrict__ lk2,
    float* __restrict__ out, int ncs) {
    const int t = blockIdx.x, b = blockIdx.y, zh = blockIdx.z;
    const int tid = threadIdx.x;
    const int nc = 1 << ncs;
    const int n = (t | 1) + 1;
    __shared__ float sl[2][64];
    __shared__ float s_lam;

    const float* recbase = part + (((size_t)(b * 64 + t) << ncs)) * 2 * REC_FLOATS;

    if (tid < 64) {
        float s1 = lq1[tid] * lk1[tid];
        float s2 = lq2[tid] * lk2[tid];
        for (int off = 32; off > 0; off >>= 1) {
            s1 += __shfl_xor(s1, off);
            s2 += __shfl_xor(s2, off);
        }
        if (tid == 0) s_lam = expf(s1) - expf(s2) + LAMBDA_INIT;
    }
    if (tid < 128) {
        int r = tid & 63, br = tid >> 6;
        float acc = 0.f;
        for (int c = 0; c < nc; ++c) {
            int lo = (c * n) >> ncs, hi = ((c + 1) * n) >> ncs;
            if (lo >= hi || lo > t) continue;
            acc += recbase[(c * 2 + br) * REC_FLOATS + r];
        }
        sl[br][r] = acc;
    }
    __syncthreads();
    const float lam = s_lam;

    float* op = out + ((size_t)b * 4096 + (size_t)t * 64) * 128;
    for (int grp = zh * 2; grp < zh * 2 + 2; ++grp) {
        int gid = grp * 256 + tid;
        int e = gid * 8;
        int row = e >> 7;
        float o1[8] = {0, 0, 0, 0, 0, 0, 0, 0}, o2[8] = {0, 0, 0, 0, 0, 0, 0, 0};
        for (int c = 0; c < nc; ++c) {
            int lo = (c * n) >> ncs, hi = ((c + 1) * n) >> ncs;
            if (lo >= hi || lo > t) continue;
            const unsigned short* O0 = (const unsigned short*)(recbase + (c * 2 + 0) * REC_FLOATS + 64);
            const unsigned short* O1 = (const unsigned short*)(recbase + (c * 2 + 1) * REC_FLOATS + 64);
            uint4 u0 = *(const uint4*)&O0[e];
            uint4 u1 = *(const uint4*)&O1[e];
            const unsigned short* e0 = (const unsigned short*)&u0;
            const unsigned short* e1 = (const unsigned short*)&u1;
            #pragma unroll
            for (int j = 0; j < 8; ++j) {
                o1[j] += bf2f(e0[j]);
                o2[j] += bf2f(e1[j]);
            }
        }
        float l1inv = 1.0f / sl[0][row], l2inv = 1.0f / sl[1][row];
        float res[8];
        #pragma unroll
        for (int j = 0; j < 8; ++j) res[j] = o1[j] * l1inv - lam * o2[j] * l2inv;
        *(float4*)&op[e] = *(float4*)&res[0];
        *(float4*)&op[e + 4] = *(float4*)&res[4];
    }
}

extern "C" void kernel_launch(void* const* d_in, const int* in_sizes, int n_in,
                              void* d_out, int out_size, void* d_ws, size_t ws_size,
                              hipStream_t stream) {
    const float* x   = (const float*)d_in[0];
    const float* Wq  = (const float*)d_in[1];
    const float* Wk  = (const float*)d_in[2];
    const float* Wv  = (const float*)d_in[3];
    const float* lq1 = (const float*)d_in[4];
    const float* lq2 = (const float*)d_in[5];
    const float* lk1 = (const float*)d_in[6];
    const float* lk2 = (const float*)d_in[7];
    float* out = (float*)d_out;
    unsigned short* qkv = (unsigned short*)d_ws;

    const int ncs = 2;  // 4 kv-chunks
    const size_t part_bytes = (size_t)256 * (1 << ncs) * 2 * REC_FLOATS * 4;
    float* part = (float*)((char*)d_ws + PART_OFF_BYTES);
    unsigned short* WT = (unsigned short*)((char*)d_ws + PART_OFF_BYTES + part_bytes);

    prep_wt<<<dim3(16, 2, 3), 256, 0, stream>>>(Wq, Wk, Wv, WT);
    qkv_fused<<<dim3(256, 2), 512, 0, stream>>>(x, WT, qkv);

    const unsigned short* qb = qkv;
    const unsigned short* kb = qkv + K_OFF;
    const unsigned short* vtb = qkv + VT_OFF;
    diff_attn_pair<<<dim3(32, 4, 2 << ncs), 256, 0, stream>>>(qb, kb, vtb, part, ncs);
    diff_combine<<<dim3(64, 4, 2), 256, 0, stream>>>(part, lq1, lq2, lk1, lk2, out, ncs);
}